// Round 16
// baseline (921.017 us; speedup 1.0000x reference)
//
#include <hip/hip_runtime.h>
#include <hip/hip_bf16.h>

typedef __hip_bfloat16 bf16;
using f32x4 = __attribute__((ext_vector_type(4))) float;
using s16x8 = __attribute__((ext_vector_type(8))) short;

#define DD 512
#define HH 2048
#define NN (2 * HH)  // interleaved gate/up output width
#define EE 8
#define BK 32
#define SLOTSZ 24576  // ring slot: A 16KB + B 8KB, seg s at s*1024

// async global->LDS, 16B per lane; lds dest is wave-uniform base + lane*16
#define GL16(g, l)                                                        \
  __builtin_amdgcn_global_load_lds(                                       \
      (const __attribute__((address_space(1))) void*)(g),                 \
      (__attribute__((address_space(3))) void*)(l), 16, 0, 0)

#define VM3 asm volatile("s_waitcnt vmcnt(3)" ::: "memory")
#define VM0 asm volatile("s_waitcnt vmcnt(0)" ::: "memory")
#define BAR() __builtin_amdgcn_s_barrier()

static __device__ __forceinline__ float silu_f(float x) {
  return x / (1.f + __expf(-x));
}

// bijective XCD swizzle (used ONLY in gemm2, where it measured best)
static __device__ __forceinline__ int xcd_swz(int bid, int nwg) {
  const int cpx = nwg >> 3;
  return (bid & 7) * cpx + (bid >> 3);
}

// ---------------------------------------------------------------------------
// W2T prep: gate/up [512][2048] fp32 -> interleaved bf16 [4096][512].
// ---------------------------------------------------------------------------
__global__ __launch_bounds__(256) void interleave_gu_kernel(
    const float* __restrict__ gk, const float* __restrict__ uk,
    bf16* __restrict__ W2T)
{
  __shared__ float tg[32][33];
  __shared__ float tu[32][33];
  const int n0 = blockIdx.x * 32;
  const int k0 = blockIdx.y * 32;
  const int tx = threadIdx.x & 31;
  const int ty = threadIdx.x >> 5;
#pragma unroll
  for (int i = 0; i < 32; i += 8) {
    tg[ty + i][tx] = gk[(size_t)(k0 + ty + i) * HH + n0 + tx];
    tu[ty + i][tx] = uk[(size_t)(k0 + ty + i) * HH + n0 + tx];
  }
  __syncthreads();
#pragma unroll
  for (int i = 0; i < 32; i += 8) {
    const int j = ty + i;
    const int rg = 2 * n0 + 32 * (j >> 4) + (j & 15);
    W2T[(size_t)rg * DD + k0 + tx] = __float2bfloat16(tg[tx][j]);
    W2T[(size_t)(rg + 16) * DD + k0 + tx] = __float2bfloat16(tu[tx][j]);
  }
}

__global__ __launch_bounds__(256) void transpose_w_kernel(
    const float* __restrict__ W, bf16* __restrict__ WT, int K, int N)
{
  __shared__ float tile[32][33];
  const int n0 = blockIdx.x * 32;
  const int k0 = blockIdx.y * 32;
  const int tx = threadIdx.x & 31;
  const int ty = threadIdx.x >> 5;
#pragma unroll
  for (int i = 0; i < 32; i += 8)
    tile[ty + i][tx] = W[(size_t)(k0 + ty + i) * N + n0 + tx];
  __syncthreads();
#pragma unroll
  for (int i = 0; i < 32; i += 8)
    WT[(size_t)(n0 + ty + i) * K + k0 + tx] = __float2bfloat16(tile[tx][ty + i]);
}

// ---------------------------------------------------------------------------
// Router + prep (unchanged, verified)
// ---------------------------------------------------------------------------
__global__ __launch_bounds__(256) void router_prep_kernel(
    const float* __restrict__ x, const float* __restrict__ rw,
    const float* __restrict__ scale, bf16* __restrict__ xs,
    float* __restrict__ a0, float* __restrict__ a1,
    float* __restrict__ part)
{
  const int lane = threadIdx.x & 63;
  const int wid = threadIdx.x >> 6;
  const int t = blockIdx.x * 4 + wid;
  __shared__ float probs_s[4][EE];

  const float4* xp = (const float4*)(x + (size_t)t * DD + lane * 8);
  float4 x0 = xp[0], x1 = xp[1];
  float xl[8] = {x0.x, x0.y, x0.z, x0.w, x1.x, x1.y, x1.z, x1.w};
  const float4* sp = (const float4*)(scale + lane * 8);
  float4 s0v = sp[0], s1v = sp[1];
  float sl[8] = {s0v.x, s0v.y, s0v.z, s0v.w, s1v.x, s1v.y, s1v.z, s1v.w};

  float rwl[64];
  const float4* rp = (const float4*)(rw + (size_t)lane * 64);
#pragma unroll
  for (int q = 0; q < 16; ++q) {
    float4 v = rp[q];
    rwl[q * 4 + 0] = v.x; rwl[q * 4 + 1] = v.y;
    rwl[q * 4 + 2] = v.z; rwl[q * 4 + 3] = v.w;
  }

  float sumsq = 0.f;
  float lg[EE] = {0.f, 0.f, 0.f, 0.f, 0.f, 0.f, 0.f, 0.f};
#pragma unroll
  for (int i = 0; i < 8; ++i) {
    float v = xl[i];
    sumsq = fmaf(v, v, sumsq);
#pragma unroll
    for (int e = 0; e < EE; ++e) lg[e] = fmaf(v, rwl[i * 8 + e], lg[e]);
  }

  bf16 xsb[8];
#pragma unroll
  for (int i = 0; i < 8; ++i) xsb[i] = __float2bfloat16(xl[i] * sl[i]);
  *(uint4*)(xs + (size_t)t * DD + lane * 8) = *(const uint4*)xsb;

#pragma unroll
  for (int off = 32; off > 0; off >>= 1) {
    sumsq += __shfl_xor(sumsq, off);
#pragma unroll
    for (int e = 0; e < EE; ++e) lg[e] += __shfl_xor(lg[e], off);
  }

  float mx = lg[0];
#pragma unroll
  for (int e = 1; e < EE; ++e) mx = fmaxf(mx, lg[e]);
  float pe[EE]; float psum = 0.f;
#pragma unroll
  for (int e = 0; e < EE; ++e) { pe[e] = __expf(lg[e] - mx); psum += pe[e]; }
  const float inv = 1.f / psum;
#pragma unroll
  for (int e = 0; e < EE; ++e) pe[e] *= inv;

  int i0 = 0; float p0 = pe[0];
#pragma unroll
  for (int e = 1; e < EE; ++e) if (pe[e] > p0) { p0 = pe[e]; i0 = e; }
  float p1 = -1.f;
#pragma unroll
  for (int e = 0; e < EE; ++e) if (e != i0 && pe[e] > p1) { p1 = pe[e]; }

  const float wsum = p0 + p1;
  const float w0 = p0 / wsum, w1 = p1 / wsum;
  const float varx = sumsq * (1.f / (float)DD);
  const float sc0 = w0 * rsqrtf(fmaf(w0 * w0, varx, 1e-6f));
  const float sc1 = w1 * rsqrtf(fmaf(w1 * w1, varx, 1e-6f));

  if (lane == 0) {
    a0[t] = sc0; a1[t] = sc1;
#pragma unroll
    for (int e = 0; e < EE; ++e) probs_s[wid][e] = pe[e];
  }
  __syncthreads();
  if (threadIdx.x < EE) {
    float s = probs_s[0][threadIdx.x] + probs_s[1][threadIdx.x] +
              probs_s[2][threadIdx.x] + probs_s[3][threadIdx.x];
    part[(size_t)blockIdx.x * EE + threadIdx.x] = s;
  }
}

__global__ __launch_bounds__(256) void loss_kernel(
    const float* __restrict__ part, int npart, float* __restrict__ loss_out,
    float invT)
{
  __shared__ float acc_s[256];
  const int tid = threadIdx.x;
  const int e = tid & 7;
  const int r = tid >> 3;
  float s = 0.f;
  for (int i = r; i < npart; i += 32) s += part[(size_t)i * EE + e];
  acc_s[tid] = s;
  __syncthreads();
  if (tid < 8) {
    float tot = 0.f;
#pragma unroll
    for (int rr = 0; rr < 32; ++rr) tot += acc_s[rr * 8 + tid];
    acc_s[tid] = tot;
  }
  __syncthreads();
  if (tid == 0) {
    float loss = 0.f;
    for (int ee = 0; ee < EE; ++ee) {
      float u = acc_s[ee] * invT;
      loss -= u * logf(u + 1e-6f);
    }
    *loss_out = loss;
  }
}

// ---------------------------------------------------------------------------
// GEMM1 v16: r13 geometry (256x128, 8 waves, T2 swizzle, natural grid) +
// 2-slot LDS ring (48KB -> 3 blocks/CU), ONE raw barrier per K-step.
// Stage for tile t+1 issued at TOP of step t -> the end-of-step vmcnt(0)
// drains loads that had the whole compute phase in flight (vs r13 where
// GL16s are issued and immediately drained between the two barriers).
// WAR: stage(t+1 -> slot (t+1)&1) overwrites slot read in step t-1, whose
// ds_reads completed before barrier B_{t-1} < stage issue. RAW: vmcnt(0)+BAR.
// ---------------------------------------------------------------------------
__global__ __launch_bounds__(512) void gemm1_kernel(
    const bf16* __restrict__ A, const bf16* __restrict__ W2,
    const float* __restrict__ gb, const float* __restrict__ ub,
    const float* __restrict__ a0v, const float* __restrict__ a1v,
    bf16* __restrict__ M)
{
  __shared__ __align__(16) char lds[2 * SLOTSZ];  // 48 KB
  __shared__ float s0s[256], s1s[256], gbs[64], ubs[64];

  const int tid = threadIdx.x;
  const int lane = tid & 63;
  const int wid = tid >> 6;            // 0..7
  const int wr = (wid >> 1) * 64;      // 0,64,128,192
  const int wc = (wid & 1) * 64;       // 0,64
  const int row0 = blockIdx.y * 256;
  const int col0 = blockIdx.x * 128;
  const int h0 = col0 >> 1;

  if (tid < 256) {
    s0s[tid] = a0v[row0 + tid];
    s1s[tid] = a1v[row0 + tid];
  } else if (tid < 320) {
    gbs[tid - 256] = gb[h0 + tid - 256];
  } else if (tid < 384) {
    ubs[tid - 320] = ub[h0 + tid - 320];
  }

  // staging sources (inverse-swizzled: row bit3 via lane&32 -> elems ^16)
  const int lr = lane >> 2;
  const int lc = ((lane & 3) * 8) ^ ((lane & 32) ? 16 : 0);
  const bf16* sp[3];
  int segoff[3];
#pragma unroll
  for (int i = 0; i < 3; ++i) {
    const int s = wid * 3 + i;
    segoff[i] = s * 1024;
    if (s < 16)
      sp[i] = A + (size_t)(row0 + s * 16 + lr) * DD + lc;
    else
      sp[i] = W2 + (size_t)(col0 + (s - 16) * 16 + lr) * DD + lc;
  }

  f32x4 acc[4][4];
  const f32x4 z4 = {0.f, 0.f, 0.f, 0.f};
#pragma unroll
  for (int m = 0; m < 4; ++m)
#pragma unroll
    for (int n = 0; n < 4; ++n) acc[m][n] = z4;

  const int fr = lane & 15;
  const int rdoff = ((lane >> 4) * 16) ^ ((fr & 8) << 2);
  const int rdA0 = (wr + fr) * 64 + rdoff;            // A region
  const int rdB0 = 16384 + (wc + fr) * 64 + rdoff;    // B region

  // prologue: stage tile 0 -> slot 0
  GL16(sp[0], lds + segoff[0]);
  GL16(sp[1], lds + segoff[1]);
  GL16(sp[2], lds + segoff[2]);
  VM0;
  BAR();

  const int NT = DD / BK;  // 16
  for (int t = 0; t < NT; ++t) {
    // issue next tile's stage first (drained at end of this step)
    if (t + 1 < NT) {
      char* wb = lds + ((t + 1) & 1) * SLOTSZ;
      GL16(sp[0] + (t + 1) * BK, wb + segoff[0]);
      GL16(sp[1] + (t + 1) * BK, wb + segoff[1]);
      GL16(sp[2] + (t + 1) * BK, wb + segoff[2]);
    }
    const char* rb = lds + (t & 1) * SLOTSZ;
    s16x8 af[4], bf_[4];
#pragma unroll
    for (int m = 0; m < 4; ++m)
      af[m] = *(const s16x8*)(rb + rdA0 + m * 1024);
#pragma unroll
    for (int n = 0; n < 4; ++n)
      bf_[n] = *(const s16x8*)(rb + rdB0 + n * 1024);
#pragma unroll
    for (int m = 0; m < 4; ++m)
#pragma unroll
      for (int n = 0; n < 4; ++n)
        acc[m][n] = __builtin_amdgcn_mfma_f32_16x16x32_bf16(af[m], bf_[n], acc[m][n], 0, 0, 0);
    if (t + 1 < NT) {
      VM0;   // drains t+1's loads, issued one full compute phase ago
      BAR();
    }
  }

  // epilogue: n-pair (2p,2p+1) = (G,U) for h = h0 + wc/2 + p*16 + fr
  const int jr = (lane >> 4) * 4;
#pragma unroll
  for (int m = 0; m < 4; ++m) {
#pragma unroll
    for (int p = 0; p < 2; ++p) {
      const int hloc = (wc >> 1) + p * 16 + fr;
      const float gbv = gbs[hloc];
      const float ubv = ubs[hloc];
      const int h = h0 + hloc;
#pragma unroll
      for (int j = 0; j < 4; ++j) {
        const int r = wr + m * 16 + jr + j;
        const float sa = s0s[r], sb = s1s[r];
        const float Gv = acc[m][2 * p][j], Uv = acc[m][2 * p + 1][j];
        const float pg0 = fmaf(sa, Gv, gbv);
        const float pu0 = fmaf(sa, Uv, ubv);
        const float pg1 = fmaf(sb, Gv, gbv);
        const float pu1 = fmaf(sb, Uv, ubv);
        const float mv = fmaf(silu_f(pg0), pu0, silu_f(pg1) * pu1);
        M[(size_t)(row0 + r) * HH + h] = __float2bfloat16(mv);
      }
    }
  }
}

// ---------------------------------------------------------------------------
// GEMM2 (round-14/15 version byte-exact): 256x128 tile, T2 swizzle, XCD
// swizzle, 3-slot LDS ring, one raw barrier per K-step, counted vmcnt(3).
// ---------------------------------------------------------------------------
__global__ __launch_bounds__(512) void gemm2_kernel(
    const bf16* __restrict__ A, const bf16* __restrict__ Bd,
    const float* __restrict__ db, float* __restrict__ out)
{
  __shared__ __align__(16) char lds[3 * SLOTSZ];
  __shared__ float dbs[128];

  const int tid = threadIdx.x;
  const int lane = tid & 63;
  const int wid = tid >> 6;
  const int wr = (wid >> 1) * 64;
  const int wc = (wid & 1) * 64;

  const int bid = xcd_swz(blockIdx.x, gridDim.x);
  const int col0 = (bid & 3) * 128;
  const int row0 = (bid >> 2) * 256;

  if (tid < 128) dbs[tid] = db[col0 + tid];

  const int lr = lane >> 2;
  const int lc = ((lane & 3) * 8) ^ ((lane & 32) ? 16 : 0);
  const bf16* sp[3];
  int segoff[3];
#pragma unroll
  for (int i = 0; i < 3; ++i) {
    const int s = wid * 3 + i;
    segoff[i] = s * 1024;
    if (s < 16)
      sp[i] = A + (size_t)(row0 + s * 16 + lr) * HH + lc;
    else
      sp[i] = Bd + (size_t)(col0 + (s - 16) * 16 + lr) * HH + lc;
  }

  f32x4 acc[4][4];
  const f32x4 z4 = {0.f, 0.f, 0.f, 0.f};
#pragma unroll
  for (int m = 0; m < 4; ++m)
#pragma unroll
    for (int n = 0; n < 4; ++n) acc[m][n] = z4;

  const int fr = lane & 15;
  const int rdoff = ((lane >> 4) * 16) ^ ((fr & 8) << 2);
  const int rdA0 = (wr + fr) * 64 + rdoff;
  const int rdB0 = 16384 + (wc + fr) * 64 + rdoff;

#pragma unroll
  for (int tt = 0; tt < 2; ++tt) {
    GL16(sp[0] + tt * BK, lds + tt * SLOTSZ + segoff[0]);
    GL16(sp[1] + tt * BK, lds + tt * SLOTSZ + segoff[1]);
    GL16(sp[2] + tt * BK, lds + tt * SLOTSZ + segoff[2]);
  }
  VM3;
  BAR();

  const int NT = HH / BK;  // 64
  int cur = 0;
  for (int t = 0; t < NT; ++t) {
    const char* rb = lds + cur * SLOTSZ;
    s16x8 af[4], bf_[4];
#pragma unroll
    for (int m = 0; m < 4; ++m)
      af[m] = *(const s16x8*)(rb + rdA0 + m * 1024);
#pragma unroll
    for (int n = 0; n < 4; ++n)
      bf_[n] = *(const s16x8*)(rb + rdB0 + n * 1024);
#pragma unroll
    for (int m = 0; m < 4; ++m)
#pragma unroll
      for (int n = 0; n < 4; ++n)
        acc[m][n] = __builtin_amdgcn_mfma_f32_16x16x32_bf16(af[m], bf_[n], acc[m][n], 0, 0, 0);

    if (t + 2 < NT) {
      const int n2 = (cur >= 1) ? cur - 1 : 2;  // (cur+2)%3
      char* wb = lds + n2 * SLOTSZ;
      GL16(sp[0] + (t + 2) * BK, wb + segoff[0]);
      GL16(sp[1] + (t + 2) * BK, wb + segoff[1]);
      GL16(sp[2] + (t + 2) * BK, wb + segoff[2]);
      VM3;
      BAR();
    } else if (t + 1 < NT) {
      VM0;
      BAR();
    }
    cur = (cur == 2) ? 0 : cur + 1;
  }

  const int jr = (lane >> 4) * 4;
#pragma unroll
  for (int m = 0; m < 4; ++m) {
#pragma unroll
    for (int n = 0; n < 4; ++n) {
      const int c = wc + n * 16 + fr;
      const float dbv = 2.f * dbs[c];
#pragma unroll
      for (int j = 0; j < 4; ++j) {
        const int r = wr + m * 16 + jr + j;
        out[(size_t)(row0 + r) * DD + col0 + c] = acc[m][n][j] + dbv;
      }
    }
  }
}

// ---------------------------------------------------------------------------
extern "C" void kernel_launch(void* const* d_in, const int* in_sizes, int n_in,
                              void* d_out, int out_size, void* d_ws, size_t ws_size,
                              hipStream_t stream)
{
  const float* x  = (const float*)d_in[0];
  const float* rw = (const float*)d_in[1];
  const float* sc = (const float*)d_in[2];
  const float* gk = (const float*)d_in[3];
  const float* gb = (const float*)d_in[4];
  const float* uk = (const float*)d_in[5];
  const float* ub = (const float*)d_in[6];
  const float* dk = (const float*)d_in[7];
  const float* db = (const float*)d_in[8];
  float* out = (float*)d_out;
  const int T = in_sizes[0] / DD;  // 65536

  char* p = (char*)d_ws;
  bf16* W2T = (bf16*)p; p += (size_t)NN * DD * sizeof(bf16);
  bf16* BdT = (bf16*)p; p += (size_t)HH * DD * sizeof(bf16);
  bf16* xs  = (bf16*)p; p += (size_t)T * DD * sizeof(bf16);
  float* a0 = (float*)p; p += (size_t)T * sizeof(float);
  float* a1 = (float*)p; p += (size_t)T * sizeof(float);
  float* part = (float*)p; p += (size_t)(T / 4) * EE * sizeof(float);
  bf16* Mbuf = (bf16*)p;
  const size_t used = (size_t)(p - (char*)d_ws);
  const size_t avail = ws_size > used ? ws_size - used : 0;
  // chunk = 32768: Mbuf 128 MB stays LLC-resident -> gemm2 reads M from
  // Infinity Cache, not HBM (measured in r6-r15).
  int chunk = 32768;
  while (chunk > 256 && (size_t)chunk * HH * sizeof(bf16) > avail) chunk >>= 1;
  if (chunk > T) chunk = T;

  interleave_gu_kernel<<<dim3(HH / 32, DD / 32), 256, 0, stream>>>(gk, uk, W2T);
  transpose_w_kernel<<<dim3(DD / 32, HH / 32), 256, 0, stream>>>(dk, BdT, HH, DD);

  router_prep_kernel<<<T / 4, 256, 0, stream>>>(x, rw, sc, xs, a0, a1, part);
  loss_kernel<<<1, 256, 0, stream>>>(part, T / 4, out + (size_t)T * DD, 1.f / (float)T);

  for (int t0 = 0; t0 < T; t0 += chunk) {
    gemm1_kernel<<<dim3(NN / 128, chunk / 256), 512, 0, stream>>>(
        xs + (size_t)t0 * DD, W2T, gb, ub, a0 + t0, a1 + t0, Mbuf);
    gemm2_kernel<<<(DD / 128) * (chunk / 256), 512, 0, stream>>>(
        Mbuf, BdT, db, out + (size_t)t0 * DD);
  }
}

// Round 17
// 808.560 us; speedup vs baseline: 1.1391x; 1.1391x over previous
//
#include <hip/hip_runtime.h>
#include <hip/hip_bf16.h>

typedef __hip_bfloat16 bf16;
using f32x4 = __attribute__((ext_vector_type(4))) float;
using s16x8 = __attribute__((ext_vector_type(8))) short;

#define DD 512
#define HH 2048
#define NN (2 * HH)  // interleaved gate/up output width
#define EE 8
#define BK 32
#define SLOTSZ 24576  // ring slot (gemm2): A 16KB + B 8KB, seg s at s*1024

// async global->LDS, 16B per lane; lds dest is wave-uniform base + lane*16
#define GL16(g, l)                                                        \
  __builtin_amdgcn_global_load_lds(                                       \
      (const __attribute__((address_space(1))) void*)(g),                 \
      (__attribute__((address_space(3))) void*)(l), 16, 0, 0)

#define VM3 asm volatile("s_waitcnt vmcnt(3)" ::: "memory")
#define VM0 asm volatile("s_waitcnt vmcnt(0)" ::: "memory")
#define BAR() __builtin_amdgcn_s_barrier()

static __device__ __forceinline__ float silu_f(float x) {
  return x / (1.f + __expf(-x));
}

// bijective XCD swizzle (used ONLY in gemm2, where it measured best)
static __device__ __forceinline__ int xcd_swz(int bid, int nwg) {
  const int cpx = nwg >> 3;
  return (bid & 7) * cpx + (bid >> 3);
}

// ---------------------------------------------------------------------------
// W2T prep: gate/up [512][2048] fp32 -> interleaved bf16 [4096][512].
// ---------------------------------------------------------------------------
__global__ __launch_bounds__(256) void interleave_gu_kernel(
    const float* __restrict__ gk, const float* __restrict__ uk,
    bf16* __restrict__ W2T)
{
  __shared__ float tg[32][33];
  __shared__ float tu[32][33];
  const int n0 = blockIdx.x * 32;
  const int k0 = blockIdx.y * 32;
  const int tx = threadIdx.x & 31;
  const int ty = threadIdx.x >> 5;
#pragma unroll
  for (int i = 0; i < 32; i += 8) {
    tg[ty + i][tx] = gk[(size_t)(k0 + ty + i) * HH + n0 + tx];
    tu[ty + i][tx] = uk[(size_t)(k0 + ty + i) * HH + n0 + tx];
  }
  __syncthreads();
#pragma unroll
  for (int i = 0; i < 32; i += 8) {
    const int j = ty + i;
    const int rg = 2 * n0 + 32 * (j >> 4) + (j & 15);
    W2T[(size_t)rg * DD + k0 + tx] = __float2bfloat16(tg[tx][j]);
    W2T[(size_t)(rg + 16) * DD + k0 + tx] = __float2bfloat16(tu[tx][j]);
  }
}

__global__ __launch_bounds__(256) void transpose_w_kernel(
    const float* __restrict__ W, bf16* __restrict__ WT, int K, int N)
{
  __shared__ float tile[32][33];
  const int n0 = blockIdx.x * 32;
  const int k0 = blockIdx.y * 32;
  const int tx = threadIdx.x & 31;
  const int ty = threadIdx.x >> 5;
#pragma unroll
  for (int i = 0; i < 32; i += 8)
    tile[ty + i][tx] = W[(size_t)(k0 + ty + i) * N + n0 + tx];
  __syncthreads();
#pragma unroll
  for (int i = 0; i < 32; i += 8)
    WT[(size_t)(n0 + ty + i) * K + k0 + tx] = __float2bfloat16(tile[tx][ty + i]);
}

// ---------------------------------------------------------------------------
// Router + prep (unchanged, verified)
// ---------------------------------------------------------------------------
__global__ __launch_bounds__(256) void router_prep_kernel(
    const float* __restrict__ x, const float* __restrict__ rw,
    const float* __restrict__ scale, bf16* __restrict__ xs,
    float* __restrict__ a0, float* __restrict__ a1,
    float* __restrict__ part)
{
  const int lane = threadIdx.x & 63;
  const int wid = threadIdx.x >> 6;
  const int t = blockIdx.x * 4 + wid;
  __shared__ float probs_s[4][EE];

  const float4* xp = (const float4*)(x + (size_t)t * DD + lane * 8);
  float4 x0 = xp[0], x1 = xp[1];
  float xl[8] = {x0.x, x0.y, x0.z, x0.w, x1.x, x1.y, x1.z, x1.w};
  const float4* sp = (const float4*)(scale + lane * 8);
  float4 s0v = sp[0], s1v = sp[1];
  float sl[8] = {s0v.x, s0v.y, s0v.z, s0v.w, s1v.x, s1v.y, s1v.z, s1v.w};

  float rwl[64];
  const float4* rp = (const float4*)(rw + (size_t)lane * 64);
#pragma unroll
  for (int q = 0; q < 16; ++q) {
    float4 v = rp[q];
    rwl[q * 4 + 0] = v.x; rwl[q * 4 + 1] = v.y;
    rwl[q * 4 + 2] = v.z; rwl[q * 4 + 3] = v.w;
  }

  float sumsq = 0.f;
  float lg[EE] = {0.f, 0.f, 0.f, 0.f, 0.f, 0.f, 0.f, 0.f};
#pragma unroll
  for (int i = 0; i < 8; ++i) {
    float v = xl[i];
    sumsq = fmaf(v, v, sumsq);
#pragma unroll
    for (int e = 0; e < EE; ++e) lg[e] = fmaf(v, rwl[i * 8 + e], lg[e]);
  }

  bf16 xsb[8];
#pragma unroll
  for (int i = 0; i < 8; ++i) xsb[i] = __float2bfloat16(xl[i] * sl[i]);
  *(uint4*)(xs + (size_t)t * DD + lane * 8) = *(const uint4*)xsb;

#pragma unroll
  for (int off = 32; off > 0; off >>= 1) {
    sumsq += __shfl_xor(sumsq, off);
#pragma unroll
    for (int e = 0; e < EE; ++e) lg[e] += __shfl_xor(lg[e], off);
  }

  float mx = lg[0];
#pragma unroll
  for (int e = 1; e < EE; ++e) mx = fmaxf(mx, lg[e]);
  float pe[EE]; float psum = 0.f;
#pragma unroll
  for (int e = 0; e < EE; ++e) { pe[e] = __expf(lg[e] - mx); psum += pe[e]; }
  const float inv = 1.f / psum;
#pragma unroll
  for (int e = 0; e < EE; ++e) pe[e] *= inv;

  int i0 = 0; float p0 = pe[0];
#pragma unroll
  for (int e = 1; e < EE; ++e) if (pe[e] > p0) { p0 = pe[e]; i0 = e; }
  float p1 = -1.f;
#pragma unroll
  for (int e = 0; e < EE; ++e) if (e != i0 && pe[e] > p1) { p1 = pe[e]; }

  const float wsum = p0 + p1;
  const float w0 = p0 / wsum, w1 = p1 / wsum;
  const float varx = sumsq * (1.f / (float)DD);
  const float sc0 = w0 * rsqrtf(fmaf(w0 * w0, varx, 1e-6f));
  const float sc1 = w1 * rsqrtf(fmaf(w1 * w1, varx, 1e-6f));

  if (lane == 0) {
    a0[t] = sc0; a1[t] = sc1;
#pragma unroll
    for (int e = 0; e < EE; ++e) probs_s[wid][e] = pe[e];
  }
  __syncthreads();
  if (threadIdx.x < EE) {
    float s = probs_s[0][threadIdx.x] + probs_s[1][threadIdx.x] +
              probs_s[2][threadIdx.x] + probs_s[3][threadIdx.x];
    part[(size_t)blockIdx.x * EE + threadIdx.x] = s;
  }
}

__global__ __launch_bounds__(256) void loss_kernel(
    const float* __restrict__ part, int npart, float* __restrict__ loss_out,
    float invT)
{
  __shared__ float acc_s[256];
  const int tid = threadIdx.x;
  const int e = tid & 7;
  const int r = tid >> 3;
  float s = 0.f;
  for (int i = r; i < npart; i += 32) s += part[(size_t)i * EE + e];
  acc_s[tid] = s;
  __syncthreads();
  if (tid < 8) {
    float tot = 0.f;
#pragma unroll
    for (int rr = 0; rr < 32; ++rr) tot += acc_s[rr * 8 + tid];
    acc_s[tid] = tot;
  }
  __syncthreads();
  if (tid == 0) {
    float loss = 0.f;
    for (int ee = 0; ee < EE; ++ee) {
      float u = acc_s[ee] * invT;
      loss -= u * logf(u + 1e-6f);
    }
    *loss_out = loss;
  }
}

// ---------------------------------------------------------------------------
// GEMM1 (round-13 version byte-exact, measured session-best 233 us/chunk):
// 256(M)x128(N) tile, 8 waves (4Mx2N), T2 both-sides swizzle, 2-barrier
// K-loop, 27KB LDS -> occ 43%. Natural 2D grid (XCD = col%8, W2T L2-pinned).
// Ledger: every occupancy-trading variant measured worse (r14 ring -16%,
// r16 2-slot -35%, r7 BK64 -20%, r10 dual-B -21%, r11 unroll -50%).
// ---------------------------------------------------------------------------
__global__ __launch_bounds__(512) void gemm1_kernel(
    const bf16* __restrict__ A, const bf16* __restrict__ W2,
    const float* __restrict__ gb, const float* __restrict__ ub,
    const float* __restrict__ a0v, const float* __restrict__ a1v,
    bf16* __restrict__ M)
{
  __shared__ __align__(16) bf16 As[256][BK];   // 16 KB
  __shared__ __align__(16) bf16 Bs[128][BK];   // 8 KB
  __shared__ float s0s[256], s1s[256], gbs[64], ubs[64];

  const int tid = threadIdx.x;
  const int lane = tid & 63;
  const int wid = tid >> 6;            // 0..7
  const int wr = (wid >> 1) * 64;      // 0,64,128,192
  const int wc = (wid & 1) * 64;       // 0,64
  const int row0 = blockIdx.y * 256;
  const int col0 = blockIdx.x * 128;
  const int h0 = col0 >> 1;

  if (tid < 256) {
    s0s[tid] = a0v[row0 + tid];
    s1s[tid] = a1v[row0 + tid];
  } else if (tid < 320) {
    gbs[tid - 256] = gb[h0 + tid - 256];
  } else if (tid < 384) {
    ubs[tid - 320] = ub[h0 + tid - 320];
  }

  // staging: 24 segments of 16 rows x 32 cols (1 KB); segs 0..15 -> As,
  // 16..23 -> Bs. Wave wid stages segs {3*wid, 3*wid+1, 3*wid+2}.
  // Inverse-swizzled source: row bit3 (lane&32) -> elems ^16.
  const int lr = lane >> 2;
  const int lc = ((lane & 3) * 8) ^ ((lane & 32) ? 16 : 0);
  const bf16* sp[3];
  bf16* ld[3];
#pragma unroll
  for (int i = 0; i < 3; ++i) {
    const int s = wid * 3 + i;
    if (s < 16) {
      sp[i] = A + (size_t)(row0 + s * 16 + lr) * DD + lc;
      ld[i] = &As[s * 16][0];
    } else {
      sp[i] = W2 + (size_t)(col0 + (s - 16) * 16 + lr) * DD + lc;
      ld[i] = &Bs[(s - 16) * 16][0];
    }
  }

  f32x4 acc[4][4];
  const f32x4 z4 = {0.f, 0.f, 0.f, 0.f};
#pragma unroll
  for (int m = 0; m < 4; ++m)
#pragma unroll
    for (int n = 0; n < 4; ++n) acc[m][n] = z4;

  const int fr = lane & 15;
  // swizzled ds_read byte offset within 64B row
  const int rdoff = ((lane >> 4) * 16) ^ ((fr & 8) << 2);

  for (int k0 = 0; k0 < DD; k0 += BK) {
    __syncthreads();
    GL16(sp[0] + k0, ld[0]);
    GL16(sp[1] + k0, ld[1]);
    GL16(sp[2] + k0, ld[2]);
    __syncthreads();
    s16x8 af[4], bf_[4];
#pragma unroll
    for (int m = 0; m < 4; ++m)
      af[m] = *(const s16x8*)((const char*)&As[wr + m * 16 + fr][0] + rdoff);
#pragma unroll
    for (int n = 0; n < 4; ++n)
      bf_[n] = *(const s16x8*)((const char*)&Bs[wc + n * 16 + fr][0] + rdoff);
#pragma unroll
    for (int m = 0; m < 4; ++m)
#pragma unroll
      for (int n = 0; n < 4; ++n)
        acc[m][n] = __builtin_amdgcn_mfma_f32_16x16x32_bf16(af[m], bf_[n], acc[m][n], 0, 0, 0);
  }

  // epilogue: n-pair (2p,2p+1) = (G,U) for h = h0 + wc/2 + p*16 + fr
  const int jr = (lane >> 4) * 4;
#pragma unroll
  for (int m = 0; m < 4; ++m) {
#pragma unroll
    for (int p = 0; p < 2; ++p) {
      const int hloc = (wc >> 1) + p * 16 + fr;
      const float gbv = gbs[hloc];
      const float ubv = ubs[hloc];
      const int h = h0 + hloc;
#pragma unroll
      for (int j = 0; j < 4; ++j) {
        const int r = wr + m * 16 + jr + j;
        const float sa = s0s[r], sb = s1s[r];
        const float Gv = acc[m][2 * p][j], Uv = acc[m][2 * p + 1][j];
        const float pg0 = fmaf(sa, Gv, gbv);
        const float pu0 = fmaf(sa, Uv, ubv);
        const float pg1 = fmaf(sb, Gv, gbv);
        const float pu1 = fmaf(sb, Uv, ubv);
        const float mv = fmaf(silu_f(pg0), pu0, silu_f(pg1) * pu1);
        M[(size_t)(row0 + r) * HH + h] = __float2bfloat16(mv);
      }
    }
  }
}

// ---------------------------------------------------------------------------
// GEMM2 (round-14/15 version byte-exact): 256x128 tile, T2 swizzle, XCD
// swizzle, 3-slot LDS ring, one raw barrier per K-step, counted vmcnt(3).
// K=2048 (64 steps amortize ring prologue); grid residency-capped anyway.
// ---------------------------------------------------------------------------
__global__ __launch_bounds__(512) void gemm2_kernel(
    const bf16* __restrict__ A, const bf16* __restrict__ Bd,
    const float* __restrict__ db, float* __restrict__ out)
{
  __shared__ __align__(16) char lds[3 * SLOTSZ];
  __shared__ float dbs[128];

  const int tid = threadIdx.x;
  const int lane = tid & 63;
  const int wid = tid >> 6;
  const int wr = (wid >> 1) * 64;
  const int wc = (wid & 1) * 64;

  const int bid = xcd_swz(blockIdx.x, gridDim.x);
  const int col0 = (bid & 3) * 128;
  const int row0 = (bid >> 2) * 256;

  if (tid < 128) dbs[tid] = db[col0 + tid];

  const int lr = lane >> 2;
  const int lc = ((lane & 3) * 8) ^ ((lane & 32) ? 16 : 0);
  const bf16* sp[3];
  int segoff[3];
#pragma unroll
  for (int i = 0; i < 3; ++i) {
    const int s = wid * 3 + i;
    segoff[i] = s * 1024;
    if (s < 16)
      sp[i] = A + (size_t)(row0 + s * 16 + lr) * HH + lc;
    else
      sp[i] = Bd + (size_t)(col0 + (s - 16) * 16 + lr) * HH + lc;
  }

  f32x4 acc[4][4];
  const f32x4 z4 = {0.f, 0.f, 0.f, 0.f};
#pragma unroll
  for (int m = 0; m < 4; ++m)
#pragma unroll
    for (int n = 0; n < 4; ++n) acc[m][n] = z4;

  const int fr = lane & 15;
  const int rdoff = ((lane >> 4) * 16) ^ ((fr & 8) << 2);
  const int rdA0 = (wr + fr) * 64 + rdoff;
  const int rdB0 = 16384 + (wc + fr) * 64 + rdoff;

#pragma unroll
  for (int tt = 0; tt < 2; ++tt) {
    GL16(sp[0] + tt * BK, lds + tt * SLOTSZ + segoff[0]);
    GL16(sp[1] + tt * BK, lds + tt * SLOTSZ + segoff[1]);
    GL16(sp[2] + tt * BK, lds + tt * SLOTSZ + segoff[2]);
  }
  VM3;
  BAR();

  const int NT = HH / BK;  // 64
  int cur = 0;
  for (int t = 0; t < NT; ++t) {
    const char* rb = lds + cur * SLOTSZ;
    s16x8 af[4], bf_[4];
#pragma unroll
    for (int m = 0; m < 4; ++m)
      af[m] = *(const s16x8*)(rb + rdA0 + m * 1024);
#pragma unroll
    for (int n = 0; n < 4; ++n)
      bf_[n] = *(const s16x8*)(rb + rdB0 + n * 1024);
#pragma unroll
    for (int m = 0; m < 4; ++m)
#pragma unroll
      for (int n = 0; n < 4; ++n)
        acc[m][n] = __builtin_amdgcn_mfma_f32_16x16x32_bf16(af[m], bf_[n], acc[m][n], 0, 0, 0);

    if (t + 2 < NT) {
      const int n2 = (cur >= 1) ? cur - 1 : 2;  // (cur+2)%3
      char* wb = lds + n2 * SLOTSZ;
      GL16(sp[0] + (t + 2) * BK, wb + segoff[0]);
      GL16(sp[1] + (t + 2) * BK, wb + segoff[1]);
      GL16(sp[2] + (t + 2) * BK, wb + segoff[2]);
      VM3;
      BAR();
    } else if (t + 1 < NT) {
      VM0;
      BAR();
    }
    cur = (cur == 2) ? 0 : cur + 1;
  }

  const int jr = (lane >> 4) * 4;
#pragma unroll
  for (int m = 0; m < 4; ++m) {
#pragma unroll
    for (int n = 0; n < 4; ++n) {
      const int c = wc + n * 16 + fr;
      const float dbv = 2.f * dbs[c];
#pragma unroll
      for (int j = 0; j < 4; ++j) {
        const int r = wr + m * 16 + jr + j;
        out[(size_t)(row0 + r) * DD + col0 + c] = acc[m][n][j] + dbv;
      }
    }
  }
}

// ---------------------------------------------------------------------------
extern "C" void kernel_launch(void* const* d_in, const int* in_sizes, int n_in,
                              void* d_out, int out_size, void* d_ws, size_t ws_size,
                              hipStream_t stream)
{
  const float* x  = (const float*)d_in[0];
  const float* rw = (const float*)d_in[1];
  const float* sc = (const float*)d_in[2];
  const float* gk = (const float*)d_in[3];
  const float* gb = (const float*)d_in[4];
  const float* uk = (const float*)d_in[5];
  const float* ub = (const float*)d_in[6];
  const float* dk = (const float*)d_in[7];
  const float* db = (const float*)d_in[8];
  float* out = (float*)d_out;
  const int T = in_sizes[0] / DD;  // 65536

  char* p = (char*)d_ws;
  bf16* W2T = (bf16*)p; p += (size_t)NN * DD * sizeof(bf16);
  bf16* BdT = (bf16*)p; p += (size_t)HH * DD * sizeof(bf16);
  bf16* xs  = (bf16*)p; p += (size_t)T * DD * sizeof(bf16);
  float* a0 = (float*)p; p += (size_t)T * sizeof(float);
  float* a1 = (float*)p; p += (size_t)T * sizeof(float);
  float* part = (float*)p; p += (size_t)(T / 4) * EE * sizeof(float);
  bf16* Mbuf = (bf16*)p;
  const size_t used = (size_t)(p - (char*)d_ws);
  const size_t avail = ws_size > used ? ws_size - used : 0;
  // chunk = 32768: Mbuf 128 MB stays LLC-resident -> gemm2 reads M from
  // Infinity Cache, not HBM (measured in r6-r15).
  int chunk = 32768;
  while (chunk > 256 && (size_t)chunk * HH * sizeof(bf16) > avail) chunk >>= 1;
  if (chunk > T) chunk = T;

  interleave_gu_kernel<<<dim3(HH / 32, DD / 32), 256, 0, stream>>>(gk, uk, W2T);
  transpose_w_kernel<<<dim3(DD / 32, HH / 32), 256, 0, stream>>>(dk, BdT, HH, DD);

  router_prep_kernel<<<T / 4, 256, 0, stream>>>(x, rw, sc, xs, a0, a1, part);
  loss_kernel<<<1, 256, 0, stream>>>(part, T / 4, out + (size_t)T * DD, 1.f / (float)T);

  for (int t0 = 0; t0 < T; t0 += chunk) {
    gemm1_kernel<<<dim3(NN / 128, chunk / 256), 512, 0, stream>>>(
        xs + (size_t)t0 * DD, W2T, gb, ub, a0 + t0, a1 + t0, Mbuf);
    gemm2_kernel<<<(DD / 128) * (chunk / 256), 512, 0, stream>>>(
        Mbuf, BdT, db, out + (size_t)t0 * DD);
  }
}

// Round 18
// 762.656 us; speedup vs baseline: 1.2076x; 1.0602x over previous
//
#include <hip/hip_runtime.h>
#include <hip/hip_bf16.h>

typedef __hip_bfloat16 bf16;
using f32x4 = __attribute__((ext_vector_type(4))) float;
using s16x8 = __attribute__((ext_vector_type(8))) short;

#define DD 512
#define HH 2048
#define NN (2 * HH)  // interleaved gate/up output width
#define EE 8
#define BK 32
#define SLOTSZ 24576  // ring slot (gemm2): A 16KB + B 8KB, seg s at s*1024

// async global->LDS, 16B per lane; lds dest is wave-uniform base + lane*16
#define GL16(g, l)                                                        \
  __builtin_amdgcn_global_load_lds(                                       \
      (const __attribute__((address_space(1))) void*)(g),                 \
      (__attribute__((address_space(3))) void*)(l), 16, 0, 0)

#define VM3 asm volatile("s_waitcnt vmcnt(3)" ::: "memory")
#define VM0 asm volatile("s_waitcnt vmcnt(0)" ::: "memory")
#define BAR() __builtin_amdgcn_s_barrier()

// fast silu: single v_rcp_f32 instead of the correctly-rounded div sequence
// (~10-14 VALU ops each; 64 per thread in gemm1's epilogue). rcp is ~1 ulp;
// output margin is ~5x (absmax 0.0078 vs threshold 0.0416).
static __device__ __forceinline__ float silu_f(float x) {
  return x * __builtin_amdgcn_rcpf(1.f + __expf(-x));
}

// bijective XCD swizzle (used ONLY in gemm2, where it measured best)
static __device__ __forceinline__ int xcd_swz(int bid, int nwg) {
  const int cpx = nwg >> 3;
  return (bid & 7) * cpx + (bid >> 3);
}

// ---------------------------------------------------------------------------
// W2T prep: gate/up [512][2048] fp32 -> interleaved bf16 [4096][512].
// ---------------------------------------------------------------------------
__global__ __launch_bounds__(256) void interleave_gu_kernel(
    const float* __restrict__ gk, const float* __restrict__ uk,
    bf16* __restrict__ W2T)
{
  __shared__ float tg[32][33];
  __shared__ float tu[32][33];
  const int n0 = blockIdx.x * 32;
  const int k0 = blockIdx.y * 32;
  const int tx = threadIdx.x & 31;
  const int ty = threadIdx.x >> 5;
#pragma unroll
  for (int i = 0; i < 32; i += 8) {
    tg[ty + i][tx] = gk[(size_t)(k0 + ty + i) * HH + n0 + tx];
    tu[ty + i][tx] = uk[(size_t)(k0 + ty + i) * HH + n0 + tx];
  }
  __syncthreads();
#pragma unroll
  for (int i = 0; i < 32; i += 8) {
    const int j = ty + i;
    const int rg = 2 * n0 + 32 * (j >> 4) + (j & 15);
    W2T[(size_t)rg * DD + k0 + tx] = __float2bfloat16(tg[tx][j]);
    W2T[(size_t)(rg + 16) * DD + k0 + tx] = __float2bfloat16(tu[tx][j]);
  }
}

__global__ __launch_bounds__(256) void transpose_w_kernel(
    const float* __restrict__ W, bf16* __restrict__ WT, int K, int N)
{
  __shared__ float tile[32][33];
  const int n0 = blockIdx.x * 32;
  const int k0 = blockIdx.y * 32;
  const int tx = threadIdx.x & 31;
  const int ty = threadIdx.x >> 5;
#pragma unroll
  for (int i = 0; i < 32; i += 8)
    tile[ty + i][tx] = W[(size_t)(k0 + ty + i) * N + n0 + tx];
  __syncthreads();
#pragma unroll
  for (int i = 0; i < 32; i += 8)
    WT[(size_t)(n0 + ty + i) * K + k0 + tx] = __float2bfloat16(tile[tx][ty + i]);
}

// ---------------------------------------------------------------------------
// Router + prep (unchanged, verified)
// ---------------------------------------------------------------------------
__global__ __launch_bounds__(256) void router_prep_kernel(
    const float* __restrict__ x, const float* __restrict__ rw,
    const float* __restrict__ scale, bf16* __restrict__ xs,
    float* __restrict__ a0, float* __restrict__ a1,
    float* __restrict__ part)
{
  const int lane = threadIdx.x & 63;
  const int wid = threadIdx.x >> 6;
  const int t = blockIdx.x * 4 + wid;
  __shared__ float probs_s[4][EE];

  const float4* xp = (const float4*)(x + (size_t)t * DD + lane * 8);
  float4 x0 = xp[0], x1 = xp[1];
  float xl[8] = {x0.x, x0.y, x0.z, x0.w, x1.x, x1.y, x1.z, x1.w};
  const float4* sp = (const float4*)(scale + lane * 8);
  float4 s0v = sp[0], s1v = sp[1];
  float sl[8] = {s0v.x, s0v.y, s0v.z, s0v.w, s1v.x, s1v.y, s1v.z, s1v.w};

  float rwl[64];
  const float4* rp = (const float4*)(rw + (size_t)lane * 64);
#pragma unroll
  for (int q = 0; q < 16; ++q) {
    float4 v = rp[q];
    rwl[q * 4 + 0] = v.x; rwl[q * 4 + 1] = v.y;
    rwl[q * 4 + 2] = v.z; rwl[q * 4 + 3] = v.w;
  }

  float sumsq = 0.f;
  float lg[EE] = {0.f, 0.f, 0.f, 0.f, 0.f, 0.f, 0.f, 0.f};
#pragma unroll
  for (int i = 0; i < 8; ++i) {
    float v = xl[i];
    sumsq = fmaf(v, v, sumsq);
#pragma unroll
    for (int e = 0; e < EE; ++e) lg[e] = fmaf(v, rwl[i * 8 + e], lg[e]);
  }

  bf16 xsb[8];
#pragma unroll
  for (int i = 0; i < 8; ++i) xsb[i] = __float2bfloat16(xl[i] * sl[i]);
  *(uint4*)(xs + (size_t)t * DD + lane * 8) = *(const uint4*)xsb;

#pragma unroll
  for (int off = 32; off > 0; off >>= 1) {
    sumsq += __shfl_xor(sumsq, off);
#pragma unroll
    for (int e = 0; e < EE; ++e) lg[e] += __shfl_xor(lg[e], off);
  }

  float mx = lg[0];
#pragma unroll
  for (int e = 1; e < EE; ++e) mx = fmaxf(mx, lg[e]);
  float pe[EE]; float psum = 0.f;
#pragma unroll
  for (int e = 0; e < EE; ++e) { pe[e] = __expf(lg[e] - mx); psum += pe[e]; }
  const float inv = 1.f / psum;
#pragma unroll
  for (int e = 0; e < EE; ++e) pe[e] *= inv;

  int i0 = 0; float p0 = pe[0];
#pragma unroll
  for (int e = 1; e < EE; ++e) if (pe[e] > p0) { p0 = pe[e]; i0 = e; }
  float p1 = -1.f;
#pragma unroll
  for (int e = 0; e < EE; ++e) if (e != i0 && pe[e] > p1) { p1 = pe[e]; }

  const float wsum = p0 + p1;
  const float w0 = p0 / wsum, w1 = p1 / wsum;
  const float varx = sumsq * (1.f / (float)DD);
  const float sc0 = w0 * rsqrtf(fmaf(w0 * w0, varx, 1e-6f));
  const float sc1 = w1 * rsqrtf(fmaf(w1 * w1, varx, 1e-6f));

  if (lane == 0) {
    a0[t] = sc0; a1[t] = sc1;
#pragma unroll
    for (int e = 0; e < EE; ++e) probs_s[wid][e] = pe[e];
  }
  __syncthreads();
  if (threadIdx.x < EE) {
    float s = probs_s[0][threadIdx.x] + probs_s[1][threadIdx.x] +
              probs_s[2][threadIdx.x] + probs_s[3][threadIdx.x];
    part[(size_t)blockIdx.x * EE + threadIdx.x] = s;
  }
}

__global__ __launch_bounds__(256) void loss_kernel(
    const float* __restrict__ part, int npart, float* __restrict__ loss_out,
    float invT)
{
  __shared__ float acc_s[256];
  const int tid = threadIdx.x;
  const int e = tid & 7;
  const int r = tid >> 3;
  float s = 0.f;
  for (int i = r; i < npart; i += 32) s += part[(size_t)i * EE + e];
  acc_s[tid] = s;
  __syncthreads();
  if (tid < 8) {
    float tot = 0.f;
#pragma unroll
    for (int rr = 0; rr < 32; ++rr) tot += acc_s[rr * 8 + tid];
    acc_s[tid] = tot;
  }
  __syncthreads();
  if (tid == 0) {
    float loss = 0.f;
    for (int ee = 0; ee < EE; ++ee) {
      float u = acc_s[ee] * invT;
      loss -= u * logf(u + 1e-6f);
    }
    *loss_out = loss;
  }
}

// ---------------------------------------------------------------------------
// GEMM1 (round-13/17 structure, measured session-best 233 us/chunk; this
// round: fast-silu epilogue only): 256(M)x128(N) tile, 8 waves (4Mx2N),
// T2 both-sides swizzle, 2-barrier K-loop, 27KB LDS -> occ 43%.
// Natural 2D grid (XCD = col%8, W2T L2-pinned).
// ---------------------------------------------------------------------------
__global__ __launch_bounds__(512) void gemm1_kernel(
    const bf16* __restrict__ A, const bf16* __restrict__ W2,
    const float* __restrict__ gb, const float* __restrict__ ub,
    const float* __restrict__ a0v, const float* __restrict__ a1v,
    bf16* __restrict__ M)
{
  __shared__ __align__(16) bf16 As[256][BK];   // 16 KB
  __shared__ __align__(16) bf16 Bs[128][BK];   // 8 KB
  __shared__ float s0s[256], s1s[256], gbs[64], ubs[64];

  const int tid = threadIdx.x;
  const int lane = tid & 63;
  const int wid = tid >> 6;            // 0..7
  const int wr = (wid >> 1) * 64;      // 0,64,128,192
  const int wc = (wid & 1) * 64;       // 0,64
  const int row0 = blockIdx.y * 256;
  const int col0 = blockIdx.x * 128;
  const int h0 = col0 >> 1;

  if (tid < 256) {
    s0s[tid] = a0v[row0 + tid];
    s1s[tid] = a1v[row0 + tid];
  } else if (tid < 320) {
    gbs[tid - 256] = gb[h0 + tid - 256];
  } else if (tid < 384) {
    ubs[tid - 320] = ub[h0 + tid - 320];
  }

  // staging: 24 segments of 16 rows x 32 cols (1 KB); segs 0..15 -> As,
  // 16..23 -> Bs. Wave wid stages segs {3*wid, 3*wid+1, 3*wid+2}.
  // Inverse-swizzled source: row bit3 (lane&32) -> elems ^16.
  const int lr = lane >> 2;
  const int lc = ((lane & 3) * 8) ^ ((lane & 32) ? 16 : 0);
  const bf16* sp[3];
  bf16* ld[3];
#pragma unroll
  for (int i = 0; i < 3; ++i) {
    const int s = wid * 3 + i;
    if (s < 16) {
      sp[i] = A + (size_t)(row0 + s * 16 + lr) * DD + lc;
      ld[i] = &As[s * 16][0];
    } else {
      sp[i] = W2 + (size_t)(col0 + (s - 16) * 16 + lr) * DD + lc;
      ld[i] = &Bs[(s - 16) * 16][0];
    }
  }

  f32x4 acc[4][4];
  const f32x4 z4 = {0.f, 0.f, 0.f, 0.f};
#pragma unroll
  for (int m = 0; m < 4; ++m)
#pragma unroll
    for (int n = 0; n < 4; ++n) acc[m][n] = z4;

  const int fr = lane & 15;
  // swizzled ds_read byte offset within 64B row
  const int rdoff = ((lane >> 4) * 16) ^ ((fr & 8) << 2);

  for (int k0 = 0; k0 < DD; k0 += BK) {
    __syncthreads();
    GL16(sp[0] + k0, ld[0]);
    GL16(sp[1] + k0, ld[1]);
    GL16(sp[2] + k0, ld[2]);
    __syncthreads();
    s16x8 af[4], bf_[4];
#pragma unroll
    for (int m = 0; m < 4; ++m)
      af[m] = *(const s16x8*)((const char*)&As[wr + m * 16 + fr][0] + rdoff);
#pragma unroll
    for (int n = 0; n < 4; ++n)
      bf_[n] = *(const s16x8*)((const char*)&Bs[wc + n * 16 + fr][0] + rdoff);
#pragma unroll
    for (int m = 0; m < 4; ++m)
#pragma unroll
      for (int n = 0; n < 4; ++n)
        acc[m][n] = __builtin_amdgcn_mfma_f32_16x16x32_bf16(af[m], bf_[n], acc[m][n], 0, 0, 0);
  }

  // epilogue: n-pair (2p,2p+1) = (G,U) for h = h0 + wc/2 + p*16 + fr
  const int jr = (lane >> 4) * 4;
#pragma unroll
  for (int m = 0; m < 4; ++m) {
#pragma unroll
    for (int p = 0; p < 2; ++p) {
      const int hloc = (wc >> 1) + p * 16 + fr;
      const float gbv = gbs[hloc];
      const float ubv = ubs[hloc];
      const int h = h0 + hloc;
#pragma unroll
      for (int j = 0; j < 4; ++j) {
        const int r = wr + m * 16 + jr + j;
        const float sa = s0s[r], sb = s1s[r];
        const float Gv = acc[m][2 * p][j], Uv = acc[m][2 * p + 1][j];
        const float pg0 = fmaf(sa, Gv, gbv);
        const float pu0 = fmaf(sa, Uv, ubv);
        const float pg1 = fmaf(sb, Gv, gbv);
        const float pu1 = fmaf(sb, Uv, ubv);
        const float mv = fmaf(silu_f(pg0), pu0, silu_f(pg1) * pu1);
        M[(size_t)(row0 + r) * HH + h] = __float2bfloat16(mv);
      }
    }
  }
}

// ---------------------------------------------------------------------------
// GEMM2 (round-14/17 version byte-exact): 256x128 tile, T2 swizzle, XCD
// swizzle, 3-slot LDS ring, one raw barrier per K-step, counted vmcnt(3).
// ---------------------------------------------------------------------------
__global__ __launch_bounds__(512) void gemm2_kernel(
    const bf16* __restrict__ A, const bf16* __restrict__ Bd,
    const float* __restrict__ db, float* __restrict__ out)
{
  __shared__ __align__(16) char lds[3 * SLOTSZ];
  __shared__ float dbs[128];

  const int tid = threadIdx.x;
  const int lane = tid & 63;
  const int wid = tid >> 6;
  const int wr = (wid >> 1) * 64;
  const int wc = (wid & 1) * 64;

  const int bid = xcd_swz(blockIdx.x, gridDim.x);
  const int col0 = (bid & 3) * 128;
  const int row0 = (bid >> 2) * 256;

  if (tid < 128) dbs[tid] = db[col0 + tid];

  const int lr = lane >> 2;
  const int lc = ((lane & 3) * 8) ^ ((lane & 32) ? 16 : 0);
  const bf16* sp[3];
  int segoff[3];
#pragma unroll
  for (int i = 0; i < 3; ++i) {
    const int s = wid * 3 + i;
    segoff[i] = s * 1024;
    if (s < 16)
      sp[i] = A + (size_t)(row0 + s * 16 + lr) * HH + lc;
    else
      sp[i] = Bd + (size_t)(col0 + (s - 16) * 16 + lr) * HH + lc;
  }

  f32x4 acc[4][4];
  const f32x4 z4 = {0.f, 0.f, 0.f, 0.f};
#pragma unroll
  for (int m = 0; m < 4; ++m)
#pragma unroll
    for (int n = 0; n < 4; ++n) acc[m][n] = z4;

  const int fr = lane & 15;
  const int rdoff = ((lane >> 4) * 16) ^ ((fr & 8) << 2);
  const int rdA0 = (wr + fr) * 64 + rdoff;
  const int rdB0 = 16384 + (wc + fr) * 64 + rdoff;

#pragma unroll
  for (int tt = 0; tt < 2; ++tt) {
    GL16(sp[0] + tt * BK, lds + tt * SLOTSZ + segoff[0]);
    GL16(sp[1] + tt * BK, lds + tt * SLOTSZ + segoff[1]);
    GL16(sp[2] + tt * BK, lds + tt * SLOTSZ + segoff[2]);
  }
  VM3;
  BAR();

  const int NT = HH / BK;  // 64
  int cur = 0;
  for (int t = 0; t < NT; ++t) {
    const char* rb = lds + cur * SLOTSZ;
    s16x8 af[4], bf_[4];
#pragma unroll
    for (int m = 0; m < 4; ++m)
      af[m] = *(const s16x8*)(rb + rdA0 + m * 1024);
#pragma unroll
    for (int n = 0; n < 4; ++n)
      bf_[n] = *(const s16x8*)(rb + rdB0 + n * 1024);
#pragma unroll
    for (int m = 0; m < 4; ++m)
#pragma unroll
      for (int n = 0; n < 4; ++n)
        acc[m][n] = __builtin_amdgcn_mfma_f32_16x16x32_bf16(af[m], bf_[n], acc[m][n], 0, 0, 0);

    if (t + 2 < NT) {
      const int n2 = (cur >= 1) ? cur - 1 : 2;  // (cur+2)%3
      char* wb = lds + n2 * SLOTSZ;
      GL16(sp[0] + (t + 2) * BK, wb + segoff[0]);
      GL16(sp[1] + (t + 2) * BK, wb + segoff[1]);
      GL16(sp[2] + (t + 2) * BK, wb + segoff[2]);
      VM3;
      BAR();
    } else if (t + 1 < NT) {
      VM0;
      BAR();
    }
    cur = (cur == 2) ? 0 : cur + 1;
  }

  const int jr = (lane >> 4) * 4;
#pragma unroll
  for (int m = 0; m < 4; ++m) {
#pragma unroll
    for (int n = 0; n < 4; ++n) {
      const int c = wc + n * 16 + fr;
      const float dbv = 2.f * dbs[c];
#pragma unroll
      for (int j = 0; j < 4; ++j) {
        const int r = wr + m * 16 + jr + j;
        out[(size_t)(row0 + r) * DD + col0 + c] = acc[m][n][j] + dbv;
      }
    }
  }
}

// ---------------------------------------------------------------------------
extern "C" void kernel_launch(void* const* d_in, const int* in_sizes, int n_in,
                              void* d_out, int out_size, void* d_ws, size_t ws_size,
                              hipStream_t stream)
{
  const float* x  = (const float*)d_in[0];
  const float* rw = (const float*)d_in[1];
  const float* sc = (const float*)d_in[2];
  const float* gk = (const float*)d_in[3];
  const float* gb = (const float*)d_in[4];
  const float* uk = (const float*)d_in[5];
  const float* ub = (const float*)d_in[6];
  const float* dk = (const float*)d_in[7];
  const float* db = (const float*)d_in[8];
  float* out = (float*)d_out;
  const int T = in_sizes[0] / DD;  // 65536

  char* p = (char*)d_ws;
  bf16* W2T = (bf16*)p; p += (size_t)NN * DD * sizeof(bf16);
  bf16* BdT = (bf16*)p; p += (size_t)HH * DD * sizeof(bf16);
  bf16* xs  = (bf16*)p; p += (size_t)T * DD * sizeof(bf16);
  float* a0 = (float*)p; p += (size_t)T * sizeof(float);
  float* a1 = (float*)p; p += (size_t)T * sizeof(float);
  float* part = (float*)p; p += (size_t)(T / 4) * EE * sizeof(float);
  bf16* Mbuf = (bf16*)p;
  const size_t used = (size_t)(p - (char*)d_ws);
  const size_t avail = ws_size > used ? ws_size - used : 0;
  // chunk = 32768: Mbuf 128 MB stays LLC-resident -> gemm2 reads M from
  // Infinity Cache, not HBM (measured in r6-r17).
  int chunk = 32768;
  while (chunk > 256 && (size_t)chunk * HH * sizeof(bf16) > avail) chunk >>= 1;
  if (chunk > T) chunk = T;

  interleave_gu_kernel<<<dim3(HH / 32, DD / 32), 256, 0, stream>>>(gk, uk, W2T);
  transpose_w_kernel<<<dim3(DD / 32, HH / 32), 256, 0, stream>>>(dk, BdT, HH, DD);

  router_prep_kernel<<<T / 4, 256, 0, stream>>>(x, rw, sc, xs, a0, a1, part);
  loss_kernel<<<1, 256, 0, stream>>>(part, T / 4, out + (size_t)T * DD, 1.f / (float)T);

  for (int t0 = 0; t0 < T; t0 += chunk) {
    gemm1_kernel<<<dim3(NN / 128, chunk / 256), 512, 0, stream>>>(
        xs + (size_t)t0 * DD, W2T, gb, ub, a0 + t0, a1 + t0, Mbuf);
    gemm2_kernel<<<(DD / 128) * (chunk / 256), 512, 0, stream>>>(
        Mbuf, BdT, db, out + (size_t)t0 * DD);
  }
}

// Round 19
// 593.571 us; speedup vs baseline: 1.5517x; 1.2849x over previous
//
#include <hip/hip_runtime.h>
#include <hip/hip_bf16.h>

typedef __hip_bfloat16 bf16;
using f32x4 = __attribute__((ext_vector_type(4))) float;
using s16x8 = __attribute__((ext_vector_type(8))) short;

#define DD 512
#define HH 2048
#define NN (2 * HH)  // interleaved gate/up output width
#define EE 8
#define BK 32
#define SLOTSZ 24576  // ring slot (gemm2): A 16KB + B 8KB, seg s at s*1024
#define TPW 16        // tokens per wave in router_prep

// async global->LDS, 16B per lane; lds dest is wave-uniform base + lane*16
#define GL16(g, l)                                                        \
  __builtin_amdgcn_global_load_lds(                                       \
      (const __attribute__((address_space(1))) void*)(g),                 \
      (__attribute__((address_space(3))) void*)(l), 16, 0, 0)

#define VM3 asm volatile("s_waitcnt vmcnt(3)" ::: "memory")
#define VM0 asm volatile("s_waitcnt vmcnt(0)" ::: "memory")
#define BAR() __builtin_amdgcn_s_barrier()

// fast silu: single v_rcp_f32 instead of the correctly-rounded div sequence.
// rcp is ~1 ulp; output margin is ~5x (absmax 0.0078 vs threshold 0.0416).
// Measured r18: -11% on gemm1, -46 us total.
static __device__ __forceinline__ float silu_f(float x) {
  return x * __builtin_amdgcn_rcpf(1.f + __expf(-x));
}

// bijective XCD swizzle (used ONLY in gemm2, where it measured best)
static __device__ __forceinline__ int xcd_swz(int bid, int nwg) {
  const int cpx = nwg >> 3;
  return (bid & 7) * cpx + (bid >> 3);
}

// ---------------------------------------------------------------------------
// W2T prep: gate/up [512][2048] fp32 -> interleaved bf16 [4096][512].
// ---------------------------------------------------------------------------
__global__ __launch_bounds__(256) void interleave_gu_kernel(
    const float* __restrict__ gk, const float* __restrict__ uk,
    bf16* __restrict__ W2T)
{
  __shared__ float tg[32][33];
  __shared__ float tu[32][33];
  const int n0 = blockIdx.x * 32;
  const int k0 = blockIdx.y * 32;
  const int tx = threadIdx.x & 31;
  const int ty = threadIdx.x >> 5;
#pragma unroll
  for (int i = 0; i < 32; i += 8) {
    tg[ty + i][tx] = gk[(size_t)(k0 + ty + i) * HH + n0 + tx];
    tu[ty + i][tx] = uk[(size_t)(k0 + ty + i) * HH + n0 + tx];
  }
  __syncthreads();
#pragma unroll
  for (int i = 0; i < 32; i += 8) {
    const int j = ty + i;
    const int rg = 2 * n0 + 32 * (j >> 4) + (j & 15);
    W2T[(size_t)rg * DD + k0 + tx] = __float2bfloat16(tg[tx][j]);
    W2T[(size_t)(rg + 16) * DD + k0 + tx] = __float2bfloat16(tu[tx][j]);
  }
}

__global__ __launch_bounds__(256) void transpose_w_kernel(
    const float* __restrict__ W, bf16* __restrict__ WT, int K, int N)
{
  __shared__ float tile[32][33];
  const int n0 = blockIdx.x * 32;
  const int k0 = blockIdx.y * 32;
  const int tx = threadIdx.x & 31;
  const int ty = threadIdx.x >> 5;
#pragma unroll
  for (int i = 0; i < 32; i += 8)
    tile[ty + i][tx] = W[(size_t)(k0 + ty + i) * N + n0 + tx];
  __syncthreads();
#pragma unroll
  for (int i = 0; i < 32; i += 8)
    WT[(size_t)(n0 + ty + i) * K + k0 + tx] = __float2bfloat16(tile[tx][ty + i]);
}

// ---------------------------------------------------------------------------
// Router + prep v19: one wave per 16 TOKENS. rw (16KB) is loaded into
// registers ONCE per wave and reused across all 16 tokens -> rw L2 traffic
// drops 16x (1 GB -> 64 MB). Per token: x-load, logits, softmax, top2,
// RMSNorm-folded scalars, xs-write; expert-usage accumulated in registers.
// ---------------------------------------------------------------------------
__global__ __launch_bounds__(256) void router_prep_kernel(
    const float* __restrict__ x, const float* __restrict__ rw,
    const float* __restrict__ scale, bf16* __restrict__ xs,
    float* __restrict__ a0, float* __restrict__ a1,
    float* __restrict__ part)
{
  const int lane = threadIdx.x & 63;
  const int wid = threadIdx.x >> 6;
  const int tbase = blockIdx.x * (4 * TPW) + wid * TPW;
  __shared__ float probs_s[4][EE];

  // rw rows 8*lane .. 8*lane+7 -> 64 contiguous floats per lane (loaded once)
  float rwl[64];
  const float4* rp = (const float4*)(rw + (size_t)lane * 64);
#pragma unroll
  for (int q = 0; q < 16; ++q) {
    float4 v = rp[q];
    rwl[q * 4 + 0] = v.x; rwl[q * 4 + 1] = v.y;
    rwl[q * 4 + 2] = v.z; rwl[q * 4 + 3] = v.w;
  }
  const float4* sp = (const float4*)(scale + lane * 8);
  float4 s0v = sp[0], s1v = sp[1];
  float sl[8] = {s0v.x, s0v.y, s0v.z, s0v.w, s1v.x, s1v.y, s1v.z, s1v.w};

  float pacc[EE] = {0.f, 0.f, 0.f, 0.f, 0.f, 0.f, 0.f, 0.f};

  for (int tk = 0; tk < TPW; ++tk) {
    const int t = tbase + tk;
    const float4* xp = (const float4*)(x + (size_t)t * DD + lane * 8);
    float4 x0 = xp[0], x1 = xp[1];
    float xl[8] = {x0.x, x0.y, x0.z, x0.w, x1.x, x1.y, x1.z, x1.w};

    float sumsq = 0.f;
    float lg[EE] = {0.f, 0.f, 0.f, 0.f, 0.f, 0.f, 0.f, 0.f};
#pragma unroll
    for (int i = 0; i < 8; ++i) {
      float v = xl[i];
      sumsq = fmaf(v, v, sumsq);
#pragma unroll
      for (int e = 0; e < EE; ++e) lg[e] = fmaf(v, rwl[i * 8 + e], lg[e]);
    }

    bf16 xsb[8];
#pragma unroll
    for (int i = 0; i < 8; ++i) xsb[i] = __float2bfloat16(xl[i] * sl[i]);
    *(uint4*)(xs + (size_t)t * DD + lane * 8) = *(const uint4*)xsb;

#pragma unroll
    for (int off = 32; off > 0; off >>= 1) {
      sumsq += __shfl_xor(sumsq, off);
#pragma unroll
      for (int e = 0; e < EE; ++e) lg[e] += __shfl_xor(lg[e], off);
    }

    float mx = lg[0];
#pragma unroll
    for (int e = 1; e < EE; ++e) mx = fmaxf(mx, lg[e]);
    float pe[EE]; float psum = 0.f;
#pragma unroll
    for (int e = 0; e < EE; ++e) { pe[e] = __expf(lg[e] - mx); psum += pe[e]; }
    const float inv = 1.f / psum;
#pragma unroll
    for (int e = 0; e < EE; ++e) {
      pe[e] *= inv;
      pacc[e] += pe[e];
    }

    int i0 = 0; float p0 = pe[0];
#pragma unroll
    for (int e = 1; e < EE; ++e) if (pe[e] > p0) { p0 = pe[e]; i0 = e; }
    float p1 = -1.f;
#pragma unroll
    for (int e = 0; e < EE; ++e) if (e != i0 && pe[e] > p1) { p1 = pe[e]; }

    const float wsum = p0 + p1;
    const float w0 = p0 / wsum, w1 = p1 / wsum;
    const float varx = sumsq * (1.f / (float)DD);
    const float sc0 = w0 * rsqrtf(fmaf(w0 * w0, varx, 1e-6f));
    const float sc1 = w1 * rsqrtf(fmaf(w1 * w1, varx, 1e-6f));

    if (lane == 0) { a0[t] = sc0; a1[t] = sc1; }
  }

  if (lane == 0) {
#pragma unroll
    for (int e = 0; e < EE; ++e) probs_s[wid][e] = pacc[e];
  }
  __syncthreads();
  if (threadIdx.x < EE) {
    float s = probs_s[0][threadIdx.x] + probs_s[1][threadIdx.x] +
              probs_s[2][threadIdx.x] + probs_s[3][threadIdx.x];
    part[(size_t)blockIdx.x * EE + threadIdx.x] = s;
  }
}

__global__ __launch_bounds__(256) void loss_kernel(
    const float* __restrict__ part, int npart, float* __restrict__ loss_out,
    float invT)
{
  __shared__ float acc_s[256];
  const int tid = threadIdx.x;
  const int e = tid & 7;
  const int r = tid >> 3;
  float s = 0.f;
  for (int i = r; i < npart; i += 32) s += part[(size_t)i * EE + e];
  acc_s[tid] = s;
  __syncthreads();
  if (tid < 8) {
    float tot = 0.f;
#pragma unroll
    for (int rr = 0; rr < 32; ++rr) tot += acc_s[rr * 8 + tid];
    acc_s[tid] = tot;
  }
  __syncthreads();
  if (tid == 0) {
    float loss = 0.f;
    for (int ee = 0; ee < EE; ++ee) {
      float u = acc_s[ee] * invT;
      loss -= u * logf(u + 1e-6f);
    }
    *loss_out = loss;
  }
}

// ---------------------------------------------------------------------------
// GEMM1 (round-18 version byte-exact, measured best 207 us/chunk):
// 256(M)x128(N) tile, 8 waves (4Mx2N), T2 both-sides swizzle, 2-barrier
// K-loop, 27KB LDS -> occ 43%, fast-silu epilogue. Natural 2D grid.
// ---------------------------------------------------------------------------
__global__ __launch_bounds__(512) void gemm1_kernel(
    const bf16* __restrict__ A, const bf16* __restrict__ W2,
    const float* __restrict__ gb, const float* __restrict__ ub,
    const float* __restrict__ a0v, const float* __restrict__ a1v,
    bf16* __restrict__ M)
{
  __shared__ __align__(16) bf16 As[256][BK];   // 16 KB
  __shared__ __align__(16) bf16 Bs[128][BK];   // 8 KB
  __shared__ float s0s[256], s1s[256], gbs[64], ubs[64];

  const int tid = threadIdx.x;
  const int lane = tid & 63;
  const int wid = tid >> 6;            // 0..7
  const int wr = (wid >> 1) * 64;      // 0,64,128,192
  const int wc = (wid & 1) * 64;       // 0,64
  const int row0 = blockIdx.y * 256;
  const int col0 = blockIdx.x * 128;
  const int h0 = col0 >> 1;

  if (tid < 256) {
    s0s[tid] = a0v[row0 + tid];
    s1s[tid] = a1v[row0 + tid];
  } else if (tid < 320) {
    gbs[tid - 256] = gb[h0 + tid - 256];
  } else if (tid < 384) {
    ubs[tid - 320] = ub[h0 + tid - 320];
  }

  const int lr = lane >> 2;
  const int lc = ((lane & 3) * 8) ^ ((lane & 32) ? 16 : 0);
  const bf16* sp[3];
  bf16* ld[3];
#pragma unroll
  for (int i = 0; i < 3; ++i) {
    const int s = wid * 3 + i;
    if (s < 16) {
      sp[i] = A + (size_t)(row0 + s * 16 + lr) * DD + lc;
      ld[i] = &As[s * 16][0];
    } else {
      sp[i] = W2 + (size_t)(col0 + (s - 16) * 16 + lr) * DD + lc;
      ld[i] = &Bs[(s - 16) * 16][0];
    }
  }

  f32x4 acc[4][4];
  const f32x4 z4 = {0.f, 0.f, 0.f, 0.f};
#pragma unroll
  for (int m = 0; m < 4; ++m)
#pragma unroll
    for (int n = 0; n < 4; ++n) acc[m][n] = z4;

  const int fr = lane & 15;
  const int rdoff = ((lane >> 4) * 16) ^ ((fr & 8) << 2);

  for (int k0 = 0; k0 < DD; k0 += BK) {
    __syncthreads();
    GL16(sp[0] + k0, ld[0]);
    GL16(sp[1] + k0, ld[1]);
    GL16(sp[2] + k0, ld[2]);
    __syncthreads();
    s16x8 af[4], bf_[4];
#pragma unroll
    for (int m = 0; m < 4; ++m)
      af[m] = *(const s16x8*)((const char*)&As[wr + m * 16 + fr][0] + rdoff);
#pragma unroll
    for (int n = 0; n < 4; ++n)
      bf_[n] = *(const s16x8*)((const char*)&Bs[wc + n * 16 + fr][0] + rdoff);
#pragma unroll
    for (int m = 0; m < 4; ++m)
#pragma unroll
      for (int n = 0; n < 4; ++n)
        acc[m][n] = __builtin_amdgcn_mfma_f32_16x16x32_bf16(af[m], bf_[n], acc[m][n], 0, 0, 0);
  }

  const int jr = (lane >> 4) * 4;
#pragma unroll
  for (int m = 0; m < 4; ++m) {
#pragma unroll
    for (int p = 0; p < 2; ++p) {
      const int hloc = (wc >> 1) + p * 16 + fr;
      const float gbv = gbs[hloc];
      const float ubv = ubs[hloc];
      const int h = h0 + hloc;
#pragma unroll
      for (int j = 0; j < 4; ++j) {
        const int r = wr + m * 16 + jr + j;
        const float sa = s0s[r], sb = s1s[r];
        const float Gv = acc[m][2 * p][j], Uv = acc[m][2 * p + 1][j];
        const float pg0 = fmaf(sa, Gv, gbv);
        const float pu0 = fmaf(sa, Uv, ubv);
        const float pg1 = fmaf(sb, Gv, gbv);
        const float pu1 = fmaf(sb, Uv, ubv);
        const float mv = fmaf(silu_f(pg0), pu0, silu_f(pg1) * pu1);
        M[(size_t)(row0 + r) * HH + h] = __float2bfloat16(mv);
      }
    }
  }
}

// ---------------------------------------------------------------------------
// GEMM2 (round-14/18 version byte-exact): 256x128 tile, T2 swizzle, XCD
// swizzle, 3-slot LDS ring, one raw barrier per K-step, counted vmcnt(3).
// ---------------------------------------------------------------------------
__global__ __launch_bounds__(512) void gemm2_kernel(
    const bf16* __restrict__ A, const bf16* __restrict__ Bd,
    const float* __restrict__ db, float* __restrict__ out)
{
  __shared__ __align__(16) char lds[3 * SLOTSZ];
  __shared__ float dbs[128];

  const int tid = threadIdx.x;
  const int lane = tid & 63;
  const int wid = tid >> 6;
  const int wr = (wid >> 1) * 64;
  const int wc = (wid & 1) * 64;

  const int bid = xcd_swz(blockIdx.x, gridDim.x);
  const int col0 = (bid & 3) * 128;
  const int row0 = (bid >> 2) * 256;

  if (tid < 128) dbs[tid] = db[col0 + tid];

  const int lr = lane >> 2;
  const int lc = ((lane & 3) * 8) ^ ((lane & 32) ? 16 : 0);
  const bf16* sp[3];
  int segoff[3];
#pragma unroll
  for (int i = 0; i < 3; ++i) {
    const int s = wid * 3 + i;
    segoff[i] = s * 1024;
    if (s < 16)
      sp[i] = A + (size_t)(row0 + s * 16 + lr) * HH + lc;
    else
      sp[i] = Bd + (size_t)(col0 + (s - 16) * 16 + lr) * HH + lc;
  }

  f32x4 acc[4][4];
  const f32x4 z4 = {0.f, 0.f, 0.f, 0.f};
#pragma unroll
  for (int m = 0; m < 4; ++m)
#pragma unroll
    for (int n = 0; n < 4; ++n) acc[m][n] = z4;

  const int fr = lane & 15;
  const int rdoff = ((lane >> 4) * 16) ^ ((fr & 8) << 2);
  const int rdA0 = (wr + fr) * 64 + rdoff;
  const int rdB0 = 16384 + (wc + fr) * 64 + rdoff;

#pragma unroll
  for (int tt = 0; tt < 2; ++tt) {
    GL16(sp[0] + tt * BK, lds + tt * SLOTSZ + segoff[0]);
    GL16(sp[1] + tt * BK, lds + tt * SLOTSZ + segoff[1]);
    GL16(sp[2] + tt * BK, lds + tt * SLOTSZ + segoff[2]);
  }
  VM3;
  BAR();

  const int NT = HH / BK;  // 64
  int cur = 0;
  for (int t = 0; t < NT; ++t) {
    const char* rb = lds + cur * SLOTSZ;
    s16x8 af[4], bf_[4];
#pragma unroll
    for (int m = 0; m < 4; ++m)
      af[m] = *(const s16x8*)(rb + rdA0 + m * 1024);
#pragma unroll
    for (int n = 0; n < 4; ++n)
      bf_[n] = *(const s16x8*)(rb + rdB0 + n * 1024);
#pragma unroll
    for (int m = 0; m < 4; ++m)
#pragma unroll
      for (int n = 0; n < 4; ++n)
        acc[m][n] = __builtin_amdgcn_mfma_f32_16x16x32_bf16(af[m], bf_[n], acc[m][n], 0, 0, 0);

    if (t + 2 < NT) {
      const int n2 = (cur >= 1) ? cur - 1 : 2;  // (cur+2)%3
      char* wb = lds + n2 * SLOTSZ;
      GL16(sp[0] + (t + 2) * BK, wb + segoff[0]);
      GL16(sp[1] + (t + 2) * BK, wb + segoff[1]);
      GL16(sp[2] + (t + 2) * BK, wb + segoff[2]);
      VM3;
      BAR();
    } else if (t + 1 < NT) {
      VM0;
      BAR();
    }
    cur = (cur == 2) ? 0 : cur + 1;
  }

  const int jr = (lane >> 4) * 4;
#pragma unroll
  for (int m = 0; m < 4; ++m) {
#pragma unroll
    for (int n = 0; n < 4; ++n) {
      const int c = wc + n * 16 + fr;
      const float dbv = 2.f * dbs[c];
#pragma unroll
      for (int j = 0; j < 4; ++j) {
        const int r = wr + m * 16 + jr + j;
        out[(size_t)(row0 + r) * DD + col0 + c] = acc[m][n][j] + dbv;
      }
    }
  }
}

// ---------------------------------------------------------------------------
extern "C" void kernel_launch(void* const* d_in, const int* in_sizes, int n_in,
                              void* d_out, int out_size, void* d_ws, size_t ws_size,
                              hipStream_t stream)
{
  const float* x  = (const float*)d_in[0];
  const float* rw = (const float*)d_in[1];
  const float* sc = (const float*)d_in[2];
  const float* gk = (const float*)d_in[3];
  const float* gb = (const float*)d_in[4];
  const float* uk = (const float*)d_in[5];
  const float* ub = (const float*)d_in[6];
  const float* dk = (const float*)d_in[7];
  const float* db = (const float*)d_in[8];
  float* out = (float*)d_out;
  const int T = in_sizes[0] / DD;  // 65536

  char* p = (char*)d_ws;
  bf16* W2T = (bf16*)p; p += (size_t)NN * DD * sizeof(bf16);
  bf16* BdT = (bf16*)p; p += (size_t)HH * DD * sizeof(bf16);
  bf16* xs  = (bf16*)p; p += (size_t)T * DD * sizeof(bf16);
  float* a0 = (float*)p; p += (size_t)T * sizeof(float);
  float* a1 = (float*)p; p += (size_t)T * sizeof(float);
  float* part = (float*)p; p += (size_t)(T / (4 * TPW)) * EE * sizeof(float);
  bf16* Mbuf = (bf16*)p;
  const size_t used = (size_t)(p - (char*)d_ws);
  const size_t avail = ws_size > used ? ws_size - used : 0;
  // chunk = 32768: Mbuf 128 MB stays LLC-resident -> gemm2 reads M from
  // Infinity Cache, not HBM (measured in r6-r18).
  int chunk = 32768;
  while (chunk > 256 && (size_t)chunk * HH * sizeof(bf16) > avail) chunk >>= 1;
  if (chunk > T) chunk = T;

  interleave_gu_kernel<<<dim3(HH / 32, DD / 32), 256, 0, stream>>>(gk, uk, W2T);
  transpose_w_kernel<<<dim3(DD / 32, HH / 32), 256, 0, stream>>>(dk, BdT, HH, DD);

  router_prep_kernel<<<T / (4 * TPW), 256, 0, stream>>>(x, rw, sc, xs, a0, a1, part);
  loss_kernel<<<1, 256, 0, stream>>>(part, T / (4 * TPW), out + (size_t)T * DD,
                                     1.f / (float)T);

  for (int t0 = 0; t0 < T; t0 += chunk) {
    gemm1_kernel<<<dim3(NN / 128, chunk / 256), 512, 0, stream>>>(
        xs + (size_t)t0 * DD, W2T, gb, ub, a0 + t0, a1 + t0, Mbuf);
    gemm2_kernel<<<(DD / 128) * (chunk / 256), 512, 0, stream>>>(
        Mbuf, BdT, db, out + (size_t)t0 * DD);
  }
}

// Round 20
// 589.915 us; speedup vs baseline: 1.5613x; 1.0062x over previous
//
#include <hip/hip_runtime.h>
#include <hip/hip_bf16.h>

typedef __hip_bfloat16 bf16;
using f32x4 = __attribute__((ext_vector_type(4))) float;
using s16x8 = __attribute__((ext_vector_type(8))) short;

#define DD 512
#define HH 2048
#define NN (2 * HH)  // interleaved gate/up output width
#define EE 8
#define BK 32
#define SLOTSZ 24576  // ring slot (gemm2): A 16KB + B 8KB, seg s at s*1024
#define TPW 16        // tokens per wave in router_prep

// async global->LDS, 16B per lane; lds dest is wave-uniform base + lane*16
#define GL16(g, l)                                                        \
  __builtin_amdgcn_global_load_lds(                                       \
      (const __attribute__((address_space(1))) void*)(g),                 \
      (__attribute__((address_space(3))) void*)(l), 16, 0, 0)

#define VM3 asm volatile("s_waitcnt vmcnt(3)" ::: "memory")
#define VM0 asm volatile("s_waitcnt vmcnt(0)" ::: "memory")
#define BAR() __builtin_amdgcn_s_barrier()

// fast silu: single v_rcp_f32 (measured r18: -11% on gemm1). ~1 ulp; output
// margin ~5x (absmax 0.0078 vs threshold 0.0416).
static __device__ __forceinline__ float silu_f(float x) {
  return x * __builtin_amdgcn_rcpf(1.f + __expf(-x));
}

// bijective XCD swizzle (used ONLY in gemm2, where it measured best)
static __device__ __forceinline__ int xcd_swz(int bid, int nwg) {
  const int cpx = nwg >> 3;
  return (bid & 7) * cpx + (bid >> 3);
}

// ---------------------------------------------------------------------------
// W2T prep: gate/up [512][2048] fp32 -> interleaved bf16 [4096][512].
// ---------------------------------------------------------------------------
__global__ __launch_bounds__(256) void interleave_gu_kernel(
    const float* __restrict__ gk, const float* __restrict__ uk,
    bf16* __restrict__ W2T)
{
  __shared__ float tg[32][33];
  __shared__ float tu[32][33];
  const int n0 = blockIdx.x * 32;
  const int k0 = blockIdx.y * 32;
  const int tx = threadIdx.x & 31;
  const int ty = threadIdx.x >> 5;
#pragma unroll
  for (int i = 0; i < 32; i += 8) {
    tg[ty + i][tx] = gk[(size_t)(k0 + ty + i) * HH + n0 + tx];
    tu[ty + i][tx] = uk[(size_t)(k0 + ty + i) * HH + n0 + tx];
  }
  __syncthreads();
#pragma unroll
  for (int i = 0; i < 32; i += 8) {
    const int j = ty + i;
    const int rg = 2 * n0 + 32 * (j >> 4) + (j & 15);
    W2T[(size_t)rg * DD + k0 + tx] = __float2bfloat16(tg[tx][j]);
    W2T[(size_t)(rg + 16) * DD + k0 + tx] = __float2bfloat16(tu[tx][j]);
  }
}

__global__ __launch_bounds__(256) void transpose_w_kernel(
    const float* __restrict__ W, bf16* __restrict__ WT, int K, int N)
{
  __shared__ float tile[32][33];
  const int n0 = blockIdx.x * 32;
  const int k0 = blockIdx.y * 32;
  const int tx = threadIdx.x & 31;
  const int ty = threadIdx.x >> 5;
#pragma unroll
  for (int i = 0; i < 32; i += 8)
    tile[ty + i][tx] = W[(size_t)(k0 + ty + i) * N + n0 + tx];
  __syncthreads();
#pragma unroll
  for (int i = 0; i < 32; i += 8)
    WT[(size_t)(n0 + ty + i) * K + k0 + tx] = __float2bfloat16(tile[tx][ty + i]);
}

// ---------------------------------------------------------------------------
// Router + prep (r19 version, measured -169 us vs 1-wave-per-token):
// one wave per 16 tokens; rw (16KB) register-resident, reused 16x.
// ---------------------------------------------------------------------------
__global__ __launch_bounds__(256) void router_prep_kernel(
    const float* __restrict__ x, const float* __restrict__ rw,
    const float* __restrict__ scale, bf16* __restrict__ xs,
    float* __restrict__ a0, float* __restrict__ a1,
    float* __restrict__ part)
{
  const int lane = threadIdx.x & 63;
  const int wid = threadIdx.x >> 6;
  const int tbase = blockIdx.x * (4 * TPW) + wid * TPW;
  __shared__ float probs_s[4][EE];

  float rwl[64];
  const float4* rp = (const float4*)(rw + (size_t)lane * 64);
#pragma unroll
  for (int q = 0; q < 16; ++q) {
    float4 v = rp[q];
    rwl[q * 4 + 0] = v.x; rwl[q * 4 + 1] = v.y;
    rwl[q * 4 + 2] = v.z; rwl[q * 4 + 3] = v.w;
  }
  const float4* sp = (const float4*)(scale + lane * 8);
  float4 s0v = sp[0], s1v = sp[1];
  float sl[8] = {s0v.x, s0v.y, s0v.z, s0v.w, s1v.x, s1v.y, s1v.z, s1v.w};

  float pacc[EE] = {0.f, 0.f, 0.f, 0.f, 0.f, 0.f, 0.f, 0.f};

  for (int tk = 0; tk < TPW; ++tk) {
    const int t = tbase + tk;
    const float4* xp = (const float4*)(x + (size_t)t * DD + lane * 8);
    float4 x0 = xp[0], x1 = xp[1];
    float xl[8] = {x0.x, x0.y, x0.z, x0.w, x1.x, x1.y, x1.z, x1.w};

    float sumsq = 0.f;
    float lg[EE] = {0.f, 0.f, 0.f, 0.f, 0.f, 0.f, 0.f, 0.f};
#pragma unroll
    for (int i = 0; i < 8; ++i) {
      float v = xl[i];
      sumsq = fmaf(v, v, sumsq);
#pragma unroll
      for (int e = 0; e < EE; ++e) lg[e] = fmaf(v, rwl[i * 8 + e], lg[e]);
    }

    bf16 xsb[8];
#pragma unroll
    for (int i = 0; i < 8; ++i) xsb[i] = __float2bfloat16(xl[i] * sl[i]);
    *(uint4*)(xs + (size_t)t * DD + lane * 8) = *(const uint4*)xsb;

#pragma unroll
    for (int off = 32; off > 0; off >>= 1) {
      sumsq += __shfl_xor(sumsq, off);
#pragma unroll
      for (int e = 0; e < EE; ++e) lg[e] += __shfl_xor(lg[e], off);
    }

    float mx = lg[0];
#pragma unroll
    for (int e = 1; e < EE; ++e) mx = fmaxf(mx, lg[e]);
    float pe[EE]; float psum = 0.f;
#pragma unroll
    for (int e = 0; e < EE; ++e) { pe[e] = __expf(lg[e] - mx); psum += pe[e]; }
    const float inv = 1.f / psum;
#pragma unroll
    for (int e = 0; e < EE; ++e) {
      pe[e] *= inv;
      pacc[e] += pe[e];
    }

    int i0 = 0; float p0 = pe[0];
#pragma unroll
    for (int e = 1; e < EE; ++e) if (pe[e] > p0) { p0 = pe[e]; i0 = e; }
    float p1 = -1.f;
#pragma unroll
    for (int e = 0; e < EE; ++e) if (e != i0 && pe[e] > p1) { p1 = pe[e]; }

    const float wsum = p0 + p1;
    const float w0 = p0 / wsum, w1 = p1 / wsum;
    const float varx = sumsq * (1.f / (float)DD);
    const float sc0 = w0 * rsqrtf(fmaf(w0 * w0, varx, 1e-6f));
    const float sc1 = w1 * rsqrtf(fmaf(w1 * w1, varx, 1e-6f));

    if (lane == 0) { a0[t] = sc0; a1[t] = sc1; }
  }

  if (lane == 0) {
#pragma unroll
    for (int e = 0; e < EE; ++e) probs_s[wid][e] = pacc[e];
  }
  __syncthreads();
  if (threadIdx.x < EE) {
    float s = probs_s[0][threadIdx.x] + probs_s[1][threadIdx.x] +
              probs_s[2][threadIdx.x] + probs_s[3][threadIdx.x];
    part[(size_t)blockIdx.x * EE + threadIdx.x] = s;
  }
}

__global__ __launch_bounds__(256) void loss_kernel(
    const float* __restrict__ part, int npart, float* __restrict__ loss_out,
    float invT)
{
  __shared__ float acc_s[256];
  const int tid = threadIdx.x;
  const int e = tid & 7;
  const int r = tid >> 3;
  float s = 0.f;
  for (int i = r; i < npart; i += 32) s += part[(size_t)i * EE + e];
  acc_s[tid] = s;
  __syncthreads();
  if (tid < 8) {
    float tot = 0.f;
#pragma unroll
    for (int rr = 0; rr < 32; ++rr) tot += acc_s[rr * 8 + tid];
    acc_s[tid] = tot;
  }
  __syncthreads();
  if (tid == 0) {
    float loss = 0.f;
    for (int ee = 0; ee < EE; ++ee) {
      float u = acc_s[ee] * invT;
      loss -= u * logf(u + 1e-6f);
    }
    *loss_out = loss;
  }
}

// ---------------------------------------------------------------------------
// GEMM1 (r18/r19 version byte-exact, measured best ~205 us/chunk):
// 256(M)x128(N), 8 waves, T2 swizzle, 2-barrier K-loop, fast-silu epilogue.
// ---------------------------------------------------------------------------
__global__ __launch_bounds__(512) void gemm1_kernel(
    const bf16* __restrict__ A, const bf16* __restrict__ W2,
    const float* __restrict__ gb, const float* __restrict__ ub,
    const float* __restrict__ a0v, const float* __restrict__ a1v,
    bf16* __restrict__ M)
{
  __shared__ __align__(16) bf16 As[256][BK];   // 16 KB
  __shared__ __align__(16) bf16 Bs[128][BK];   // 8 KB
  __shared__ float s0s[256], s1s[256], gbs[64], ubs[64];

  const int tid = threadIdx.x;
  const int lane = tid & 63;
  const int wid = tid >> 6;
  const int wr = (wid >> 1) * 64;
  const int wc = (wid & 1) * 64;
  const int row0 = blockIdx.y * 256;
  const int col0 = blockIdx.x * 128;
  const int h0 = col0 >> 1;

  if (tid < 256) {
    s0s[tid] = a0v[row0 + tid];
    s1s[tid] = a1v[row0 + tid];
  } else if (tid < 320) {
    gbs[tid - 256] = gb[h0 + tid - 256];
  } else if (tid < 384) {
    ubs[tid - 320] = ub[h0 + tid - 320];
  }

  const int lr = lane >> 2;
  const int lc = ((lane & 3) * 8) ^ ((lane & 32) ? 16 : 0);
  const bf16* sp[3];
  bf16* ld[3];
#pragma unroll
  for (int i = 0; i < 3; ++i) {
    const int s = wid * 3 + i;
    if (s < 16) {
      sp[i] = A + (size_t)(row0 + s * 16 + lr) * DD + lc;
      ld[i] = &As[s * 16][0];
    } else {
      sp[i] = W2 + (size_t)(col0 + (s - 16) * 16 + lr) * DD + lc;
      ld[i] = &Bs[(s - 16) * 16][0];
    }
  }

  f32x4 acc[4][4];
  const f32x4 z4 = {0.f, 0.f, 0.f, 0.f};
#pragma unroll
  for (int m = 0; m < 4; ++m)
#pragma unroll
    for (int n = 0; n < 4; ++n) acc[m][n] = z4;

  const int fr = lane & 15;
  const int rdoff = ((lane >> 4) * 16) ^ ((fr & 8) << 2);

  for (int k0 = 0; k0 < DD; k0 += BK) {
    __syncthreads();
    GL16(sp[0] + k0, ld[0]);
    GL16(sp[1] + k0, ld[1]);
    GL16(sp[2] + k0, ld[2]);
    __syncthreads();
    s16x8 af[4], bf_[4];
#pragma unroll
    for (int m = 0; m < 4; ++m)
      af[m] = *(const s16x8*)((const char*)&As[wr + m * 16 + fr][0] + rdoff);
#pragma unroll
    for (int n = 0; n < 4; ++n)
      bf_[n] = *(const s16x8*)((const char*)&Bs[wc + n * 16 + fr][0] + rdoff);
#pragma unroll
    for (int m = 0; m < 4; ++m)
#pragma unroll
      for (int n = 0; n < 4; ++n)
        acc[m][n] = __builtin_amdgcn_mfma_f32_16x16x32_bf16(af[m], bf_[n], acc[m][n], 0, 0, 0);
  }

  const int jr = (lane >> 4) * 4;
#pragma unroll
  for (int m = 0; m < 4; ++m) {
#pragma unroll
    for (int p = 0; p < 2; ++p) {
      const int hloc = (wc >> 1) + p * 16 + fr;
      const float gbv = gbs[hloc];
      const float ubv = ubs[hloc];
      const int h = h0 + hloc;
#pragma unroll
      for (int j = 0; j < 4; ++j) {
        const int r = wr + m * 16 + jr + j;
        const float sa = s0s[r], sb = s1s[r];
        const float Gv = acc[m][2 * p][j], Uv = acc[m][2 * p + 1][j];
        const float pg0 = fmaf(sa, Gv, gbv);
        const float pu0 = fmaf(sa, Uv, ubv);
        const float pg1 = fmaf(sb, Gv, gbv);
        const float pu1 = fmaf(sb, Uv, ubv);
        const float mv = fmaf(silu_f(pg0), pu0, silu_f(pg1) * pu1);
        M[(size_t)(row0 + r) * HH + h] = __float2bfloat16(mv);
      }
    }
  }
}

// ---------------------------------------------------------------------------
// GEMM2 (r14-18 structure + T5 setprio around the MFMA cluster — the ring's
// phase split gives waves role diversity the scheduler can arbitrate):
// 256x128 tile, T2 swizzle, XCD swizzle, 3-slot ring, counted vmcnt(3).
// ---------------------------------------------------------------------------
__global__ __launch_bounds__(512) void gemm2_kernel(
    const bf16* __restrict__ A, const bf16* __restrict__ Bd,
    const float* __restrict__ db, float* __restrict__ out)
{
  __shared__ __align__(16) char lds[3 * SLOTSZ];
  __shared__ float dbs[128];

  const int tid = threadIdx.x;
  const int lane = tid & 63;
  const int wid = tid >> 6;
  const int wr = (wid >> 1) * 64;
  const int wc = (wid & 1) * 64;

  const int bid = xcd_swz(blockIdx.x, gridDim.x);
  const int col0 = (bid & 3) * 128;
  const int row0 = (bid >> 2) * 256;

  if (tid < 128) dbs[tid] = db[col0 + tid];

  const int lr = lane >> 2;
  const int lc = ((lane & 3) * 8) ^ ((lane & 32) ? 16 : 0);
  const bf16* sp[3];
  int segoff[3];
#pragma unroll
  for (int i = 0; i < 3; ++i) {
    const int s = wid * 3 + i;
    segoff[i] = s * 1024;
    if (s < 16)
      sp[i] = A + (size_t)(row0 + s * 16 + lr) * HH + lc;
    else
      sp[i] = Bd + (size_t)(col0 + (s - 16) * 16 + lr) * HH + lc;
  }

  f32x4 acc[4][4];
  const f32x4 z4 = {0.f, 0.f, 0.f, 0.f};
#pragma unroll
  for (int m = 0; m < 4; ++m)
#pragma unroll
    for (int n = 0; n < 4; ++n) acc[m][n] = z4;

  const int fr = lane & 15;
  const int rdoff = ((lane >> 4) * 16) ^ ((fr & 8) << 2);
  const int rdA0 = (wr + fr) * 64 + rdoff;
  const int rdB0 = 16384 + (wc + fr) * 64 + rdoff;

#pragma unroll
  for (int tt = 0; tt < 2; ++tt) {
    GL16(sp[0] + tt * BK, lds + tt * SLOTSZ + segoff[0]);
    GL16(sp[1] + tt * BK, lds + tt * SLOTSZ + segoff[1]);
    GL16(sp[2] + tt * BK, lds + tt * SLOTSZ + segoff[2]);
  }
  VM3;
  BAR();

  const int NT = HH / BK;  // 64
  int cur = 0;
  for (int t = 0; t < NT; ++t) {
    const char* rb = lds + cur * SLOTSZ;
    s16x8 af[4], bf_[4];
#pragma unroll
    for (int m = 0; m < 4; ++m)
      af[m] = *(const s16x8*)(rb + rdA0 + m * 1024);
#pragma unroll
    for (int n = 0; n < 4; ++n)
      bf_[n] = *(const s16x8*)(rb + rdB0 + n * 1024);
    __builtin_amdgcn_s_setprio(1);
#pragma unroll
    for (int m = 0; m < 4; ++m)
#pragma unroll
      for (int n = 0; n < 4; ++n)
        acc[m][n] = __builtin_amdgcn_mfma_f32_16x16x32_bf16(af[m], bf_[n], acc[m][n], 0, 0, 0);
    __builtin_amdgcn_s_setprio(0);

    if (t + 2 < NT) {
      const int n2 = (cur >= 1) ? cur - 1 : 2;  // (cur+2)%3
      char* wb = lds + n2 * SLOTSZ;
      GL16(sp[0] + (t + 2) * BK, wb + segoff[0]);
      GL16(sp[1] + (t + 2) * BK, wb + segoff[1]);
      GL16(sp[2] + (t + 2) * BK, wb + segoff[2]);
      VM3;
      BAR();
    } else if (t + 1 < NT) {
      VM0;
      BAR();
    }
    cur = (cur == 2) ? 0 : cur + 1;
  }

  const int jr = (lane >> 4) * 4;
#pragma unroll
  for (int m = 0; m < 4; ++m) {
#pragma unroll
    for (int n = 0; n < 4; ++n) {
      const int c = wc + n * 16 + fr;
      const float dbv = 2.f * dbs[c];
#pragma unroll
      for (int j = 0; j < 4; ++j) {
        const int r = wr + m * 16 + jr + j;
        out[(size_t)(row0 + r) * DD + col0 + c] = acc[m][n][j] + dbv;
      }
    }
  }
}

// ---------------------------------------------------------------------------
extern "C" void kernel_launch(void* const* d_in, const int* in_sizes, int n_in,
                              void* d_out, int out_size, void* d_ws, size_t ws_size,
                              hipStream_t stream)
{
  const float* x  = (const float*)d_in[0];
  const float* rw = (const float*)d_in[1];
  const float* sc = (const float*)d_in[2];
  const float* gk = (const float*)d_in[3];
  const float* gb = (const float*)d_in[4];
  const float* uk = (const float*)d_in[5];
  const float* ub = (const float*)d_in[6];
  const float* dk = (const float*)d_in[7];
  const float* db = (const float*)d_in[8];
  float* out = (float*)d_out;
  const int T = in_sizes[0] / DD;  // 65536

  char* p = (char*)d_ws;
  bf16* W2T = (bf16*)p; p += (size_t)NN * DD * sizeof(bf16);
  bf16* BdT = (bf16*)p; p += (size_t)HH * DD * sizeof(bf16);
  bf16* xs  = (bf16*)p; p += (size_t)T * DD * sizeof(bf16);
  float* a0 = (float*)p; p += (size_t)T * sizeof(float);
  float* a1 = (float*)p; p += (size_t)T * sizeof(float);
  float* part = (float*)p; p += (size_t)(T / (4 * TPW)) * EE * sizeof(float);
  bf16* Mbuf = (bf16*)p;
  const size_t used = (size_t)(p - (char*)d_ws);
  const size_t avail = ws_size > used ? ws_size - used : 0;
  // chunk = 32768: Mbuf 128 MB stays LLC-resident -> gemm2 reads M from
  // Infinity Cache, not HBM (measured in r6-r19).
  int chunk = 32768;
  while (chunk > 256 && (size_t)chunk * HH * sizeof(bf16) > avail) chunk >>= 1;
  if (chunk > T) chunk = T;

  interleave_gu_kernel<<<dim3(HH / 32, DD / 32), 256, 0, stream>>>(gk, uk, W2T);
  transpose_w_kernel<<<dim3(DD / 32, HH / 32), 256, 0, stream>>>(dk, BdT, HH, DD);

  router_prep_kernel<<<T / (4 * TPW), 256, 0, stream>>>(x, rw, sc, xs, a0, a1, part);
  loss_kernel<<<1, 256, 0, stream>>>(part, T / (4 * TPW), out + (size_t)T * DD,
                                     1.f / (float)T);

  for (int t0 = 0; t0 < T; t0 += chunk) {
    gemm1_kernel<<<dim3(NN / 128, chunk / 256), 512, 0, stream>>>(
        xs + (size_t)t0 * DD, W2T, gb, ub, a0 + t0, a1 + t0, Mbuf);
    gemm2_kernel<<<(DD / 128) * (chunk / 256), 512, 0, stream>>>(
        Mbuf, BdT, db, out + (size_t)t0 * DD);
  }
}